// Round 2
// baseline (592.227 us; speedup 1.0000x reference)
//
#include <hip/hip_runtime.h>
#include <stdint.h>

#define NB 8
#define NC 192
#define NOC 576
#define NH 4
#define HW 16384
#define NCHUNK 16

typedef unsigned short u16;
typedef __bf16 v8bf __attribute__((ext_vector_type(8)));
typedef float v4f __attribute__((ext_vector_type(4)));
typedef u16 v8us __attribute__((ext_vector_type(8)));

__device__ __forceinline__ u16 f2bf(float f) {
    uint32_t u = __float_as_uint(f);
    u += 0x7FFFu + ((u >> 16) & 1u);
    return (u16)(u >> 16);
}
__device__ __forceinline__ float bf2f(u16 u) {
    return __uint_as_float(((uint32_t)u) << 16);
}

// ---------------- P: convert w_qkv to bf16 ----------------
__global__ void k_cvt_w(const float* __restrict__ w, u16* __restrict__ wb, int n) {
    int i = blockIdx.x * 256 + threadIdx.x;
    if (i < n) wb[i] = f2bf(w[i]);
}

// ---------------- A: qkv_raw[bl][oc][p] = W[oc][c] @ (x+f)[b0+bl][c][p] ----------------
// BM=576 (whole W, frags from global/L2), BN=32 pixels staged in LDS (swizzled), K=192.
__global__ __launch_bounds__(256) void k_gemm_qkv(
    const float* __restrict__ x, const float* __restrict__ f,
    const u16* __restrict__ wb, u16* __restrict__ qkv, int b0)
{
    __shared__ u16 bt[32 * 192];
    const int t = threadIdx.x;
    const int bl = blockIdx.y;
    const int bg = b0 + bl;
    const int p0 = blockIdx.x * 32;

    // stage B tile: 32 pixels x 192 channels, [pix][ch] with XOR-swizzled 16B chunks
    {
        const int px = t & 31;
        const int cg = t >> 5;              // 0..7
        #pragma unroll
        for (int it = 0; it < 3; ++it) {
            const int c4 = it * 8 + cg;     // 0..23
            const size_t base = ((size_t)bg * NC + c4 * 8) * HW + p0 + px;
            v8us pk;
            #pragma unroll
            for (int j = 0; j < 8; ++j) {
                float v = x[base + (size_t)j * HW] + f[base + (size_t)j * HW];
                pk[j] = f2bf(v);
            }
            *reinterpret_cast<v8us*>(&bt[px * 192 + ((c4 ^ (px & 7)) << 3)]) = pk;
        }
    }
    __syncthreads();

    const int w = t >> 6, l = t & 63, lr = l & 15, lg = l >> 4;
    const int m0 = w * 144;                  // 4 waves x 144 rows = 576

    v4f acc[9][2];
    #pragma unroll
    for (int mi = 0; mi < 9; ++mi)
        #pragma unroll
        for (int ni = 0; ni < 2; ++ni)
            acc[mi][ni] = (v4f){0.f, 0.f, 0.f, 0.f};

    #pragma unroll
    for (int ks = 0; ks < 6; ++ks) {
        const int k = ks * 32 + lg * 8;
        v8bf a[9], bb[2];
        #pragma unroll
        for (int mi = 0; mi < 9; ++mi)
            a[mi] = *reinterpret_cast<const v8bf*>(&wb[(m0 + mi * 16 + lr) * 192 + k]);
        #pragma unroll
        for (int ni = 0; ni < 2; ++ni) {
            const int px = ni * 16 + lr;
            const int c4 = ks * 4 + lg;
            bb[ni] = *reinterpret_cast<const v8bf*>(&bt[px * 192 + ((c4 ^ (px & 7)) << 3)]);
        }
        #pragma unroll
        for (int mi = 0; mi < 9; ++mi)
            #pragma unroll
            for (int ni = 0; ni < 2; ++ni)
                acc[mi][ni] = __builtin_amdgcn_mfma_f32_16x16x32_bf16(a[mi], bb[ni], acc[mi][ni], 0, 0, 0);
    }

    #pragma unroll
    for (int mi = 0; mi < 9; ++mi)
        #pragma unroll
        for (int ni = 0; ni < 2; ++ni)
            #pragma unroll
            for (int r = 0; r < 4; ++r) {
                const int oc = m0 + mi * 16 + lg * 4 + r;
                const int px = p0 + ni * 16 + lr;
                qkv[((size_t)bl * NOC + oc) * HW + px] = f2bf(acc[mi][ni][r]);
            }
}

// ---------------- B: depthwise 3x3 + sum-of-squares ----------------
// one (bl,ch) 128x128 plane per block; q,k planes -> d_out scratch (bf16), v -> ws
__global__ __launch_bounds__(256) void k_dw(
    const u16* __restrict__ qkv, const float* __restrict__ wdw,
    u16* __restrict__ qk_out, u16* __restrict__ v_out,
    float* __restrict__ sumsq, int b0)
{
    __shared__ u16 plane[128 * 136];
    __shared__ float red[4];
    const int t = threadIdx.x;
    const int ch = blockIdx.x;
    const int bl = blockIdx.y;
    const int bg = b0 + bl;
    const size_t pbase = ((size_t)bl * NOC + ch) * HW;

    float wk[9];
    #pragma unroll
    for (int i = 0; i < 9; ++i) wk[i] = wdw[ch * 9 + i];

    const int r = t >> 1;
    const int cb = (t & 1) * 64;

    #pragma unroll
    for (int i = 0; i < 8; ++i) {
        v8us v = *reinterpret_cast<const v8us*>(&qkv[pbase + r * 128 + cb + i * 8]);
        *reinterpret_cast<v8us*>(&plane[r * 136 + cb + i * 8]) = v;
    }
    __syncthreads();

    const bool vm = (r > 0), vp = (r < 127);
    const u16* rowm = &plane[(r - 1) * 136];
    const u16* rowc = &plane[r * 136];
    const u16* rowp = &plane[(r + 1) * 136];

    float am, ac, bm, bc, cm, cc2;
    if (cb == 0) { am = 0.f; bm = 0.f; cm = 0.f; }
    else {
        am = vm ? bf2f(rowm[cb - 1]) : 0.f;
        bm = bf2f(rowc[cb - 1]);
        cm = vp ? bf2f(rowp[cb - 1]) : 0.f;
    }
    ac = vm ? bf2f(rowm[cb]) : 0.f;
    bc = bf2f(rowc[cb]);
    cc2 = vp ? bf2f(rowp[cb]) : 0.f;

    uint32_t ov[32];
    float ssq = 0.f;
    #pragma unroll
    for (int xp = 0; xp < 32; ++xp) {
        float o2[2];
        #pragma unroll
        for (int s2 = 0; s2 < 2; ++s2) {
            const int col = cb + xp * 2 + s2;
            float ap, bp, cp;
            if (col < 127) {
                ap = vm ? bf2f(rowm[col + 1]) : 0.f;
                bp = bf2f(rowc[col + 1]);
                cp = vp ? bf2f(rowp[col + 1]) : 0.f;
            } else { ap = 0.f; bp = 0.f; cp = 0.f; }
            float o = wk[0]*am + wk[1]*ac + wk[2]*ap
                    + wk[3]*bm + wk[4]*bc + wk[5]*bp
                    + wk[6]*cm + wk[7]*cc2 + wk[8]*cp;
            u16 ob = f2bf(o);
            float orr = bf2f(ob);          // consistent with what Gram/GEMM consume
            ssq += orr * orr;
            o2[s2] = 0.f;
            ov[xp] = (s2 == 0) ? (uint32_t)ob : (ov[xp] | ((uint32_t)ob << 16));
            am = ac; ac = ap; bm = bc; bc = bp; cm = cc2; cc2 = cp;
        }
    }

    __syncthreads();   // all neighbor reads done
    #pragma unroll
    for (int i = 0; i < 32; ++i)
        *reinterpret_cast<uint32_t*>(&plane[r * 136 + cb + i * 2]) = ov[i];
    __syncthreads();

    u16* dst = (ch < 2 * NC) ? (qk_out + ((size_t)bg * (2 * NC) + ch) * HW)
                             : (v_out + ((size_t)bg * NC + (ch - 2 * NC)) * HW);
    // 256 threads x 8 elem x 8 iters = 16384 elements
    #pragma unroll
    for (int i = 0; i < 8; ++i) {
        const int idx = i * 2048 + t * 8;
        const int rr = idx >> 7, cc = idx & 127;
        v8us v = *reinterpret_cast<const v8us*>(&plane[rr * 136 + cc]);
        *reinterpret_cast<v8us*>(&dst[idx]) = v;
    }

    #pragma unroll
    for (int off = 32; off > 0; off >>= 1) ssq += __shfl_down(ssq, off);
    if ((t & 63) == 0) red[t >> 6] = ssq;
    __syncthreads();
    if (t == 0 && ch < 2 * NC) sumsq[bg * (2 * NC) + ch] = red[0] + red[1] + red[2] + red[3];
}

// ---------------- C: partial Gram matrices q@k^T over pixel chunks ----------------
__global__ __launch_bounds__(256) void k_attn(
    const u16* __restrict__ qk, float* __restrict__ partials)
{
    __shared__ float wsum[4 * 2304];
    const int t = threadIdx.x;
    const int chunk = blockIdx.x;   // 0..15
    const int h = blockIdx.y;
    const int b = blockIdx.z;
    const int w = t >> 6, l = t & 63, lr = l & 15, lg = l >> 4;

    const size_t qbase = ((size_t)b * 384 + h * 48) * HW;
    const size_t kbase = ((size_t)b * 384 + 192 + h * 48) * HW;
    const int pb = chunk * 1024 + w * 256;

    v4f acc[3][3];
    #pragma unroll
    for (int mi = 0; mi < 3; ++mi)
        #pragma unroll
        for (int ni = 0; ni < 3; ++ni)
            acc[mi][ni] = (v4f){0.f, 0.f, 0.f, 0.f};

    #pragma unroll
    for (int ks = 0; ks < 8; ++ks) {
        const int k = pb + ks * 32 + lg * 8;
        v8bf a[3], bb[3];
        #pragma unroll
        for (int mi = 0; mi < 3; ++mi)
            a[mi] = *reinterpret_cast<const v8bf*>(&qk[qbase + (size_t)(mi * 16 + lr) * HW + k]);
        #pragma unroll
        for (int ni = 0; ni < 3; ++ni)
            bb[ni] = *reinterpret_cast<const v8bf*>(&qk[kbase + (size_t)(ni * 16 + lr) * HW + k]);
        #pragma unroll
        for (int mi = 0; mi < 3; ++mi)
            #pragma unroll
            for (int ni = 0; ni < 3; ++ni)
                acc[mi][ni] = __builtin_amdgcn_mfma_f32_16x16x32_bf16(a[mi], bb[ni], acc[mi][ni], 0, 0, 0);
    }

    #pragma unroll
    for (int mi = 0; mi < 3; ++mi)
        #pragma unroll
        for (int ni = 0; ni < 3; ++ni)
            #pragma unroll
            for (int r = 0; r < 4; ++r)
                wsum[w * 2304 + (mi * 16 + lg * 4 + r) * 48 + ni * 16 + lr] = acc[mi][ni][r];
    __syncthreads();

    #pragma unroll
    for (int i = 0; i < 9; ++i) {
        const int e = t + i * 256;
        float s = wsum[e] + wsum[2304 + e] + wsum[4608 + e] + wsum[6912 + e];
        partials[(((size_t)(b * NH + h)) * NCHUNK + chunk) * 2304 + e] = s;
    }
}

// ---------------- C2: normalize + softmax + M = Wproj @ blockdiag(attn) ----------------
__global__ __launch_bounds__(256) void k_smx(
    const float* __restrict__ partials, const float* __restrict__ sumsq,
    const float* __restrict__ wproj, const float* __restrict__ temp,
    u16* __restrict__ Mb)
{
    __shared__ float att[2304];
    __shared__ float rq[48], rk[48];
    const int t = threadIdx.x;
    const int b = blockIdx.x;

    for (int h = 0; h < NH; ++h) {
        if (t < 48) {
            float s = sumsq[b * 384 + h * 48 + t];
            rq[t] = 1.f / fmaxf(sqrtf(s), 1e-12f);
        } else if (t < 96) {
            float s = sumsq[b * 384 + 192 + h * 48 + (t - 48)];
            rk[t - 48] = 1.f / fmaxf(sqrtf(s), 1e-12f);
        }
        __syncthreads();
        const float tp = temp[h];
        #pragma unroll
        for (int i = 0; i < 9; ++i) {
            const int e = t + i * 256;
            float s = 0.f;
            for (int c = 0; c < NCHUNK; ++c)
                s += partials[(((size_t)(b * NH + h)) * NCHUNK + c) * 2304 + e];
            att[e] = s * rq[e / 48] * rk[e % 48] * tp;
        }
        __syncthreads();
        if (t < 48) {
            float m = -1e30f;
            for (int j = 0; j < 48; ++j) m = fmaxf(m, att[t * 48 + j]);
            float s = 0.f;
            for (int j = 0; j < 48; ++j) { float e2 = __expf(att[t * 48 + j] - m); att[t * 48 + j] = e2; s += e2; }
            const float inv = 1.f / s;
            for (int j = 0; j < 48; ++j) att[t * 48 + j] *= inv;
        }
        __syncthreads();
        #pragma unroll
        for (int i = 0; i < 36; ++i) {
            const int idx = t + i * 256;     // 192*48
            const int oc = idx / 48, d = idx % 48;
            float s = 0.f;
            for (int cc = 0; cc < 48; ++cc)
                s += wproj[oc * 192 + h * 48 + cc] * att[cc * 48 + d];
            Mb[((size_t)b * NC + oc) * NC + h * 48 + d] = f2bf(s);
        }
        __syncthreads();
    }
}

// ---------------- D: out[b] = M[b] @ v[b], fp32 out ----------------
__global__ __launch_bounds__(256) void k_gemm_out(
    const u16* __restrict__ vp, const u16* __restrict__ Mb,
    float* __restrict__ out)
{
    __shared__ u16 bt[64 * 192];
    const int t = threadIdx.x;
    const int b = blockIdx.y;
    const int p0 = blockIdx.x * 64;

    {
        const int px = t & 63;
        const int cg = t >> 6;             // 0..3
        #pragma unroll
        for (int it = 0; it < 6; ++it) {
            const int c4 = it * 4 + cg;    // 0..23
            const size_t base = ((size_t)b * NC + c4 * 8) * HW + p0 + px;
            v8us pk;
            #pragma unroll
            for (int j = 0; j < 8; ++j) pk[j] = vp[base + (size_t)j * HW];
            *reinterpret_cast<v8us*>(&bt[px * 192 + ((c4 ^ (px & 7)) << 3)]) = pk;
        }
    }
    __syncthreads();

    const int w = t >> 6, l = t & 63, lr = l & 15, lg = l >> 4;
    const int m0 = w * 48;                 // 4 waves x 48 rows = 192

    v4f acc[3][4];
    #pragma unroll
    for (int mi = 0; mi < 3; ++mi)
        #pragma unroll
        for (int ni = 0; ni < 4; ++ni)
            acc[mi][ni] = (v4f){0.f, 0.f, 0.f, 0.f};

    #pragma unroll
    for (int ks = 0; ks < 6; ++ks) {
        const int k = ks * 32 + lg * 8;
        v8bf a[3], bb[4];
        #pragma unroll
        for (int mi = 0; mi < 3; ++mi)
            a[mi] = *reinterpret_cast<const v8bf*>(&Mb[((size_t)b * NC + m0 + mi * 16 + lr) * NC + k]);
        #pragma unroll
        for (int ni = 0; ni < 4; ++ni) {
            const int px = ni * 16 + lr;
            const int c4 = ks * 4 + lg;
            bb[ni] = *reinterpret_cast<const v8bf*>(&bt[px * 192 + ((c4 ^ (px & 7)) << 3)]);
        }
        #pragma unroll
        for (int mi = 0; mi < 3; ++mi)
            #pragma unroll
            for (int ni = 0; ni < 4; ++ni)
                acc[mi][ni] = __builtin_amdgcn_mfma_f32_16x16x32_bf16(a[mi], bb[ni], acc[mi][ni], 0, 0, 0);
    }

    #pragma unroll
    for (int mi = 0; mi < 3; ++mi)
        #pragma unroll
        for (int ni = 0; ni < 4; ++ni)
            #pragma unroll
            for (int r = 0; r < 4; ++r) {
                const int oc = m0 + mi * 16 + lg * 4 + r;
                const int px = p0 + ni * 16 + lr;
                out[((size_t)b * NC + oc) * HW + px] = acc[mi][ni][r];
            }
}

extern "C" void kernel_launch(void* const* d_in, const int* in_sizes, int n_in,
                              void* d_out, int out_size, void* d_ws, size_t ws_size,
                              hipStream_t stream)
{
    (void)in_sizes; (void)n_in; (void)out_size;
    const float* x      = (const float*)d_in[0];
    const float* f      = (const float*)d_in[1];
    const float* w_qkv  = (const float*)d_in[2];
    const float* w_dw   = (const float*)d_in[3];
    const float* w_proj = (const float*)d_in[4];
    const float* temp   = (const float*)d_in[5];

    // ws layout: fixed small stuff + v first, then adaptive qkv staging region
    char* ws = (char*)d_ws;
    u16*   vws      = (u16*)(ws);                      // 8*192*16384*2 = 50,331,648
    u16*   wb       = (u16*)(ws + 50331648);           // 576*192*2     =    221,184
    float* sumsq    = (float*)(ws + 50552832);         // 8*384*4       =     12,288
    float* partials = (float*)(ws + 50565120);         // 8*4*16*2304*4 =  4,718,592
    u16*   Mb       = (u16*)(ws + 55283712);           // 8*192*192*2   =    589,824
    const size_t FIXED = 55873536;
    const size_t PERB  = (size_t)NOC * HW * 2;         // 18,874,368 per batch
    u16*   qkv_raw  = (u16*)(ws + FIXED);

    int g = 1;
    if (ws_size > FIXED + PERB) {
        size_t avail = (ws_size - FIXED) / PERB;
        g = (int)(avail > 8 ? 8 : avail);
        if (g < 1) g = 1;
    }

    u16* qk_scratch = (u16*)d_out;   // q,k planes (bf16) — exactly fills d_out, consumed before final GEMM
    float* out      = (float*)d_out;

    hipLaunchKernelGGL(k_cvt_w, dim3(432), dim3(256), 0, stream, w_qkv, wb, NOC * NC);
    for (int b0 = 0; b0 < NB; b0 += g) {
        const int nb = (b0 + g <= NB) ? g : (NB - b0);
        hipLaunchKernelGGL(k_gemm_qkv, dim3(HW / 32, nb), dim3(256), 0, stream, x, f, wb, qkv_raw, b0);
        hipLaunchKernelGGL(k_dw, dim3(NOC, nb), dim3(256), 0, stream, qkv_raw, w_dw, qk_scratch, vws, sumsq, b0);
    }
    hipLaunchKernelGGL(k_attn, dim3(NCHUNK, NH, NB), dim3(256), 0, stream, qk_scratch, partials);
    hipLaunchKernelGGL(k_smx, dim3(NB), dim3(256), 0, stream, partials, sumsq, w_proj, temp, Mb);
    hipLaunchKernelGGL(k_gemm_out, dim3(HW / 64, NB), dim3(256), 0, stream, vws, Mb, out);
}

// Round 3
// 359.403 us; speedup vs baseline: 1.6478x; 1.6478x over previous
//
#include <hip/hip_runtime.h>
#include <stdint.h>

#define NB 8
#define NC 192
#define NOC 576
#define NH 4
#define HW 16384
#define NCHUNK 16

typedef unsigned short u16;
typedef __bf16 v8bf __attribute__((ext_vector_type(8)));
typedef float v4f __attribute__((ext_vector_type(4)));
typedef u16 v8us __attribute__((ext_vector_type(8)));

__device__ __forceinline__ u16 f2bf(float f) {
    uint32_t u = __float_as_uint(f);
    u += 0x7FFFu + ((u >> 16) & 1u);
    return (u16)(u >> 16);
}
__device__ __forceinline__ float bf2f(u16 u) {
    return __uint_as_float(((uint32_t)u) << 16);
}

// ---------------- P: convert w_qkv to bf16 ----------------
__global__ void k_cvt_w(const float* __restrict__ w, u16* __restrict__ wb, int n) {
    int i = blockIdx.x * 256 + threadIdx.x;
    if (i < n) wb[i] = f2bf(w[i]);
}

// ---------------- A: qkv_raw[bl][oc][p] = W[oc][c] @ (x+f)[b0+bl][c][p] ----------------
// BM=576 (whole W, frags from global/L2), BN=32 pixels staged in LDS (swizzled), K=192.
__global__ __launch_bounds__(256) void k_gemm_qkv(
    const float* __restrict__ x, const float* __restrict__ f,
    const u16* __restrict__ wb, u16* __restrict__ qkv, int b0)
{
    __shared__ u16 bt[32 * 192];
    const int t = threadIdx.x;
    const int bl = blockIdx.y;
    const int bg = b0 + bl;
    const int p0 = blockIdx.x * 32;

    // stage B tile: 32 pixels x 192 channels, [pix][ch] with XOR-swizzled 16B chunks
    {
        const int px = t & 31;
        const int cg = t >> 5;              // 0..7
        #pragma unroll
        for (int it = 0; it < 3; ++it) {
            const int c4 = it * 8 + cg;     // 0..23
            const size_t base = ((size_t)bg * NC + c4 * 8) * HW + p0 + px;
            v8us pk;
            #pragma unroll
            for (int j = 0; j < 8; ++j) {
                float v = x[base + (size_t)j * HW] + f[base + (size_t)j * HW];
                pk[j] = f2bf(v);
            }
            *reinterpret_cast<v8us*>(&bt[px * 192 + ((c4 ^ (px & 7)) << 3)]) = pk;
        }
    }
    __syncthreads();

    const int w = t >> 6, l = t & 63, lr = l & 15, lg = l >> 4;
    const int m0 = w * 144;                  // 4 waves x 144 rows = 576

    v4f acc[9][2];
    #pragma unroll
    for (int mi = 0; mi < 9; ++mi)
        #pragma unroll
        for (int ni = 0; ni < 2; ++ni)
            acc[mi][ni] = (v4f){0.f, 0.f, 0.f, 0.f};

    #pragma unroll
    for (int ks = 0; ks < 6; ++ks) {
        const int k = ks * 32 + lg * 8;
        v8bf a[9], bb[2];
        #pragma unroll
        for (int mi = 0; mi < 9; ++mi)
            a[mi] = *reinterpret_cast<const v8bf*>(&wb[(m0 + mi * 16 + lr) * 192 + k]);
        #pragma unroll
        for (int ni = 0; ni < 2; ++ni) {
            const int px = ni * 16 + lr;
            const int c4 = ks * 4 + lg;
            bb[ni] = *reinterpret_cast<const v8bf*>(&bt[px * 192 + ((c4 ^ (px & 7)) << 3)]);
        }
        #pragma unroll
        for (int mi = 0; mi < 9; ++mi)
            #pragma unroll
            for (int ni = 0; ni < 2; ++ni)
                acc[mi][ni] = __builtin_amdgcn_mfma_f32_16x16x32_bf16(a[mi], bb[ni], acc[mi][ni], 0, 0, 0);
    }

    #pragma unroll
    for (int mi = 0; mi < 9; ++mi)
        #pragma unroll
        for (int ni = 0; ni < 2; ++ni)
            #pragma unroll
            for (int r = 0; r < 4; ++r) {
                const int oc = m0 + mi * 16 + lg * 4 + r;
                const int px = p0 + ni * 16 + lr;
                qkv[((size_t)bl * NOC + oc) * HW + px] = f2bf(acc[mi][ni][r]);
            }
}

// ---------------- B: depthwise 3x3 + sum-of-squares ----------------
// one (bl,ch) 128x128 plane per block; q,k planes -> d_out scratch (bf16), v -> ws
__global__ __launch_bounds__(256) void k_dw(
    const u16* __restrict__ qkv, const float* __restrict__ wdw,
    u16* __restrict__ qk_out, u16* __restrict__ v_out,
    float* __restrict__ sumsq, int b0)
{
    __shared__ u16 plane[128 * 136];
    __shared__ float red[4];
    const int t = threadIdx.x;
    const int ch = blockIdx.x;
    const int bl = blockIdx.y;
    const int bg = b0 + bl;
    const size_t pbase = ((size_t)bl * NOC + ch) * HW;

    float wk[9];
    #pragma unroll
    for (int i = 0; i < 9; ++i) wk[i] = wdw[ch * 9 + i];

    const int r = t >> 1;
    const int cb = (t & 1) * 64;

    #pragma unroll
    for (int i = 0; i < 8; ++i) {
        v8us v = *reinterpret_cast<const v8us*>(&qkv[pbase + r * 128 + cb + i * 8]);
        *reinterpret_cast<v8us*>(&plane[r * 136 + cb + i * 8]) = v;
    }
    __syncthreads();

    const bool vm = (r > 0), vp = (r < 127);
    const u16* rowm = &plane[(r - 1) * 136];
    const u16* rowc = &plane[r * 136];
    const u16* rowp = &plane[(r + 1) * 136];

    float am, ac, bm, bc, cm, cc2;
    if (cb == 0) { am = 0.f; bm = 0.f; cm = 0.f; }
    else {
        am = vm ? bf2f(rowm[cb - 1]) : 0.f;
        bm = bf2f(rowc[cb - 1]);
        cm = vp ? bf2f(rowp[cb - 1]) : 0.f;
    }
    ac = vm ? bf2f(rowm[cb]) : 0.f;
    bc = bf2f(rowc[cb]);
    cc2 = vp ? bf2f(rowp[cb]) : 0.f;

    uint32_t ov[32];
    float ssq = 0.f;
    #pragma unroll
    for (int xp = 0; xp < 32; ++xp) {
        #pragma unroll
        for (int s2 = 0; s2 < 2; ++s2) {
            const int col = cb + xp * 2 + s2;
            float ap, bp, cp;
            if (col < 127) {
                ap = vm ? bf2f(rowm[col + 1]) : 0.f;
                bp = bf2f(rowc[col + 1]);
                cp = vp ? bf2f(rowp[col + 1]) : 0.f;
            } else { ap = 0.f; bp = 0.f; cp = 0.f; }
            float o = wk[0]*am + wk[1]*ac + wk[2]*ap
                    + wk[3]*bm + wk[4]*bc + wk[5]*bp
                    + wk[6]*cm + wk[7]*cc2 + wk[8]*cp;
            u16 ob = f2bf(o);
            float orr = bf2f(ob);          // consistent with what Gram/GEMM consume
            ssq += orr * orr;
            ov[xp] = (s2 == 0) ? (uint32_t)ob : (ov[xp] | ((uint32_t)ob << 16));
            am = ac; ac = ap; bm = bc; bc = bp; cm = cc2; cc2 = cp;
        }
    }

    __syncthreads();   // all neighbor reads done
    #pragma unroll
    for (int i = 0; i < 32; ++i)
        *reinterpret_cast<uint32_t*>(&plane[r * 136 + cb + i * 2]) = ov[i];
    __syncthreads();

    u16* dst = (ch < 2 * NC) ? (qk_out + ((size_t)bg * (2 * NC) + ch) * HW)
                             : (v_out + ((size_t)bg * NC + (ch - 2 * NC)) * HW);
    // 256 threads x 8 elem x 8 iters = 16384 elements
    #pragma unroll
    for (int i = 0; i < 8; ++i) {
        const int idx = i * 2048 + t * 8;
        const int rr = idx >> 7, cc = idx & 127;
        v8us v = *reinterpret_cast<const v8us*>(&plane[rr * 136 + cc]);
        *reinterpret_cast<v8us*>(&dst[idx]) = v;
    }

    #pragma unroll
    for (int off = 32; off > 0; off >>= 1) ssq += __shfl_down(ssq, off);
    if ((t & 63) == 0) red[t >> 6] = ssq;
    __syncthreads();
    if (t == 0 && ch < 2 * NC) sumsq[bg * (2 * NC) + ch] = red[0] + red[1] + red[2] + red[3];
}

// ---------------- C: partial Gram matrices q@k^T over pixel chunks ----------------
__global__ __launch_bounds__(256) void k_attn(
    const u16* __restrict__ qk, float* __restrict__ partials)
{
    __shared__ float wsum[4 * 2304];
    const int t = threadIdx.x;
    const int chunk = blockIdx.x;   // 0..15
    const int h = blockIdx.y;
    const int b = blockIdx.z;
    const int w = t >> 6, l = t & 63, lr = l & 15, lg = l >> 4;

    const size_t qbase = ((size_t)b * 384 + h * 48) * HW;
    const size_t kbase = ((size_t)b * 384 + 192 + h * 48) * HW;
    const int pb = chunk * 1024 + w * 256;

    v4f acc[3][3];
    #pragma unroll
    for (int mi = 0; mi < 3; ++mi)
        #pragma unroll
        for (int ni = 0; ni < 3; ++ni)
            acc[mi][ni] = (v4f){0.f, 0.f, 0.f, 0.f};

    #pragma unroll
    for (int ks = 0; ks < 8; ++ks) {
        const int k = pb + ks * 32 + lg * 8;
        v8bf a[3], bb[3];
        #pragma unroll
        for (int mi = 0; mi < 3; ++mi)
            a[mi] = *reinterpret_cast<const v8bf*>(&qk[qbase + (size_t)(mi * 16 + lr) * HW + k]);
        #pragma unroll
        for (int ni = 0; ni < 3; ++ni)
            bb[ni] = *reinterpret_cast<const v8bf*>(&qk[kbase + (size_t)(ni * 16 + lr) * HW + k]);
        #pragma unroll
        for (int mi = 0; mi < 3; ++mi)
            #pragma unroll
            for (int ni = 0; ni < 3; ++ni)
                acc[mi][ni] = __builtin_amdgcn_mfma_f32_16x16x32_bf16(a[mi], bb[ni], acc[mi][ni], 0, 0, 0);
    }

    #pragma unroll
    for (int mi = 0; mi < 3; ++mi)
        #pragma unroll
        for (int ni = 0; ni < 3; ++ni)
            #pragma unroll
            for (int r = 0; r < 4; ++r)
                wsum[w * 2304 + (mi * 16 + lg * 4 + r) * 48 + ni * 16 + lr] = acc[mi][ni][r];
    __syncthreads();

    #pragma unroll
    for (int i = 0; i < 9; ++i) {
        const int e = t + i * 256;
        float s = wsum[e] + wsum[2304 + e] + wsum[4608 + e] + wsum[6912 + e];
        partials[(((size_t)(b * NH + h)) * NCHUNK + chunk) * 2304 + e] = s;
    }
}

// ---------------- C2: normalize + softmax + M = Wproj @ blockdiag(attn) ----------------
// one block per (h, b): 32 blocks
__global__ __launch_bounds__(256) void k_smx(
    const float* __restrict__ partials, const float* __restrict__ sumsq,
    const float* __restrict__ wproj, const float* __restrict__ temp,
    u16* __restrict__ Mb)
{
    __shared__ float att[2304];
    __shared__ float rq[48], rk[48];
    const int t = threadIdx.x;
    const int h = blockIdx.x;
    const int b = blockIdx.y;

    if (t < 48) {
        float s = sumsq[b * 384 + h * 48 + t];
        rq[t] = 1.f / fmaxf(sqrtf(s), 1e-12f);
    } else if (t < 96) {
        float s = sumsq[b * 384 + 192 + h * 48 + (t - 48)];
        rk[t - 48] = 1.f / fmaxf(sqrtf(s), 1e-12f);
    }
    __syncthreads();
    const float tp = temp[h];
    #pragma unroll
    for (int i = 0; i < 9; ++i) {
        const int e = t + i * 256;
        const float* pp = &partials[(((size_t)(b * NH + h)) * NCHUNK) * 2304 + e];
        float s = 0.f;
        #pragma unroll
        for (int c = 0; c < NCHUNK; ++c) s += pp[(size_t)c * 2304];
        att[e] = s * rq[e / 48] * rk[e % 48] * tp;
    }
    __syncthreads();
    if (t < 48) {
        float m = -1e30f;
        #pragma unroll
        for (int j = 0; j < 48; ++j) m = fmaxf(m, att[t * 48 + j]);
        float s = 0.f;
        for (int j = 0; j < 48; ++j) { float e2 = __expf(att[t * 48 + j] - m); att[t * 48 + j] = e2; s += e2; }
        const float inv = 1.f / s;
        for (int j = 0; j < 48; ++j) att[t * 48 + j] *= inv;
    }
    __syncthreads();
    #pragma unroll
    for (int i = 0; i < 36; ++i) {
        const int idx = t + i * 256;     // 192*48 outputs
        const int oc = idx / 48, d = idx % 48;
        float s = 0.f;
        #pragma unroll
        for (int cc = 0; cc < 48; ++cc)
            s += wproj[oc * 192 + h * 48 + cc] * att[cc * 48 + d];
        Mb[((size_t)b * NC + oc) * NC + h * 48 + d] = f2bf(s);
    }
}

// ---------------- D: out[b] = M[b] @ v[b], fp32 out ----------------
__global__ __launch_bounds__(256) void k_gemm_out(
    const u16* __restrict__ vp, const u16* __restrict__ Mb,
    float* __restrict__ out)
{
    __shared__ u16 bt[64 * 192];
    const int t = threadIdx.x;
    const int b = blockIdx.y;
    const int p0 = blockIdx.x * 64;

    {
        const int px = t & 63;
        const int cg = t >> 6;             // 0..3
        #pragma unroll
        for (int it = 0; it < 6; ++it) {
            const int c4 = it * 4 + cg;    // 0..23
            const size_t base = ((size_t)b * NC + c4 * 8) * HW + p0 + px;
            v8us pk;
            #pragma unroll
            for (int j = 0; j < 8; ++j) pk[j] = vp[base + (size_t)j * HW];
            *reinterpret_cast<v8us*>(&bt[px * 192 + ((c4 ^ (px & 7)) << 3)]) = pk;
        }
    }
    __syncthreads();

    const int w = t >> 6, l = t & 63, lr = l & 15, lg = l >> 4;
    const int m0 = w * 48;                 // 4 waves x 48 rows = 192

    v4f acc[3][4];
    #pragma unroll
    for (int mi = 0; mi < 3; ++mi)
        #pragma unroll
        for (int ni = 0; ni < 4; ++ni)
            acc[mi][ni] = (v4f){0.f, 0.f, 0.f, 0.f};

    #pragma unroll
    for (int ks = 0; ks < 6; ++ks) {
        const int k = ks * 32 + lg * 8;
        v8bf a[3], bb[4];
        #pragma unroll
        for (int mi = 0; mi < 3; ++mi)
            a[mi] = *reinterpret_cast<const v8bf*>(&Mb[((size_t)b * NC + m0 + mi * 16 + lr) * NC + k]);
        #pragma unroll
        for (int ni = 0; ni < 4; ++ni) {
            const int px = ni * 16 + lr;
            const int c4 = ks * 4 + lg;
            bb[ni] = *reinterpret_cast<const v8bf*>(&bt[px * 192 + ((c4 ^ (px & 7)) << 3)]);
        }
        #pragma unroll
        for (int mi = 0; mi < 3; ++mi)
            #pragma unroll
            for (int ni = 0; ni < 4; ++ni)
                acc[mi][ni] = __builtin_amdgcn_mfma_f32_16x16x32_bf16(a[mi], bb[ni], acc[mi][ni], 0, 0, 0);
    }

    #pragma unroll
    for (int mi = 0; mi < 3; ++mi)
        #pragma unroll
        for (int ni = 0; ni < 4; ++ni)
            #pragma unroll
            for (int r = 0; r < 4; ++r) {
                const int oc = m0 + mi * 16 + lg * 4 + r;
                const int px = p0 + ni * 16 + lr;
                out[((size_t)b * NC + oc) * HW + px] = acc[mi][ni][r];
            }
}

extern "C" void kernel_launch(void* const* d_in, const int* in_sizes, int n_in,
                              void* d_out, int out_size, void* d_ws, size_t ws_size,
                              hipStream_t stream)
{
    (void)in_sizes; (void)n_in; (void)out_size;
    const float* x      = (const float*)d_in[0];
    const float* f      = (const float*)d_in[1];
    const float* w_qkv  = (const float*)d_in[2];
    const float* w_dw   = (const float*)d_in[3];
    const float* w_proj = (const float*)d_in[4];
    const float* temp   = (const float*)d_in[5];

    // ws layout: fixed small stuff + v first, then adaptive qkv staging region
    char* ws = (char*)d_ws;
    u16*   vws      = (u16*)(ws);                      // 8*192*16384*2 = 50,331,648
    u16*   wb       = (u16*)(ws + 50331648);           // 576*192*2     =    221,184
    float* sumsq    = (float*)(ws + 50552832);         // 8*384*4       =     12,288
    float* partials = (float*)(ws + 50565120);         // 8*4*16*2304*4 =  4,718,592
    u16*   Mb       = (u16*)(ws + 55283712);           // 8*192*192*2   =    589,824
    const size_t FIXED = 55873536;
    const size_t PERB  = (size_t)NOC * HW * 2;         // 18,874,368 per batch
    u16*   qkv_raw  = (u16*)(ws + FIXED);

    int g = 1;
    if (ws_size > FIXED + PERB) {
        size_t avail = (ws_size - FIXED) / PERB;
        g = (int)(avail > 8 ? 8 : avail);
        if (g < 1) g = 1;
    }

    u16* qk_scratch = (u16*)d_out;   // q,k planes (bf16) — exactly fills d_out, consumed before final GEMM
    float* out      = (float*)d_out;

    hipLaunchKernelGGL(k_cvt_w, dim3(432), dim3(256), 0, stream, w_qkv, wb, NOC * NC);
    for (int b0 = 0; b0 < NB; b0 += g) {
        const int nb = (b0 + g <= NB) ? g : (NB - b0);
        hipLaunchKernelGGL(k_gemm_qkv, dim3(HW / 32, nb), dim3(256), 0, stream, x, f, wb, qkv_raw, b0);
        hipLaunchKernelGGL(k_dw, dim3(NOC, nb), dim3(256), 0, stream, qkv_raw, w_dw, qk_scratch, vws, sumsq, b0);
    }
    hipLaunchKernelGGL(k_attn, dim3(NCHUNK, NH, NB), dim3(256), 0, stream, qk_scratch, partials);
    hipLaunchKernelGGL(k_smx, dim3(NH, NB), dim3(256), 0, stream, partials, sumsq, w_proj, temp, Mb);
    hipLaunchKernelGGL(k_gemm_out, dim3(HW / 64, NB), dim3(256), 0, stream, vws, Mb, out);
}

// Round 4
// 355.141 us; speedup vs baseline: 1.6676x; 1.0120x over previous
//
#include <hip/hip_runtime.h>
#include <stdint.h>

#define NB 8
#define NC 192
#define NOC 576
#define NH 4
#define HW 16384
#define NCHUNK 16

typedef unsigned short u16;
typedef __bf16 v8bf __attribute__((ext_vector_type(8)));
typedef float v4f __attribute__((ext_vector_type(4)));
typedef u16 v8us __attribute__((ext_vector_type(8)));
typedef u16 v4us __attribute__((ext_vector_type(4)));

__device__ __forceinline__ u16 f2bf(float f) {
    uint32_t u = __float_as_uint(f);
    u += 0x7FFFu + ((u >> 16) & 1u);
    return (u16)(u >> 16);
}
__device__ __forceinline__ float bf2f(u16 u) {
    return __uint_as_float(((uint32_t)u) << 16);
}

// ---------------- P: convert w_qkv to bf16 ----------------
__global__ void k_cvt_w(const float* __restrict__ w, u16* __restrict__ wb, int n) {
    int i = blockIdx.x * 256 + threadIdx.x;
    if (i < n) wb[i] = f2bf(w[i]);
}

// ---------------- A: qkv_raw[bl][oc][p] = W[oc][c] @ (x+f)[b0+bl][c][p] ----------------
// Swapped MFMA roles: D rows = pixels (vectorized 8B stores), D cols = oc.
// BN=64 pixels staged in LDS [px][ch] (XOR-swizzled 16B chunks); W frags from L2.
__global__ __launch_bounds__(256, 2) void k_gemm_qkv(
    const float* __restrict__ x, const float* __restrict__ f,
    const u16* __restrict__ wb, u16* __restrict__ qkv, int b0)
{
    __shared__ u16 bt[64 * 192];
    const int t = threadIdx.x;
    const int bl = blockIdx.y;
    const int bg = b0 + bl;
    const int p0 = blockIdx.x * 64;

    // stage: 64 px x 192 ch, float4 coalesced loads (16 lanes x 16B = 256B/ch-row)
    {
        const int qp = t & 15;          // pixel quad 0..15
        const int chw = t >> 4;         // 0..15
        const int px = qp * 4;
        #pragma unroll
        for (int pass = 0; pass < 12; ++pass) {
            const int ch = pass * 16 + chw;
            const size_t base = ((size_t)bg * NC + ch) * HW + p0 + px;
            const float4 xv = *reinterpret_cast<const float4*>(&x[base]);
            const float4 fv = *reinterpret_cast<const float4*>(&f[base]);
            const int c4 = ch >> 3, cl = ch & 7;
            bt[(px + 0) * 192 + ((c4 ^ ((px + 0) & 7)) << 3) + cl] = f2bf(xv.x + fv.x);
            bt[(px + 1) * 192 + ((c4 ^ ((px + 1) & 7)) << 3) + cl] = f2bf(xv.y + fv.y);
            bt[(px + 2) * 192 + ((c4 ^ ((px + 2) & 7)) << 3) + cl] = f2bf(xv.z + fv.z);
            bt[(px + 3) * 192 + ((c4 ^ ((px + 3) & 7)) << 3) + cl] = f2bf(xv.w + fv.w);
        }
    }
    __syncthreads();

    const int w = t >> 6, l = t & 63, lr = l & 15, lg = l >> 4;
    const int oc0 = w * 144;                 // 4 waves x 144 oc = 576

    v4f acc[4][9];
    #pragma unroll
    for (int mi = 0; mi < 4; ++mi)
        #pragma unroll
        for (int ni = 0; ni < 9; ++ni)
            acc[mi][ni] = (v4f){0.f, 0.f, 0.f, 0.f};

    #pragma unroll
    for (int ks = 0; ks < 6; ++ks) {
        const int k = ks * 32 + lg * 8;
        const int c4 = ks * 4 + lg;
        v8bf a[4];
        #pragma unroll
        for (int mi = 0; mi < 4; ++mi) {
            const int px = mi * 16 + lr;
            a[mi] = *reinterpret_cast<const v8bf*>(&bt[px * 192 + ((c4 ^ (px & 7)) << 3)]);
        }
        #pragma unroll
        for (int ni = 0; ni < 9; ++ni) {
            const int oc = oc0 + ni * 16 + lr;
            const v8bf bw = *reinterpret_cast<const v8bf*>(&wb[oc * 192 + k]);
            #pragma unroll
            for (int mi = 0; mi < 4; ++mi)
                acc[mi][ni] = __builtin_amdgcn_mfma_f32_16x16x32_bf16(a[mi], bw, acc[mi][ni], 0, 0, 0);
        }
    }

    #pragma unroll
    for (int mi = 0; mi < 4; ++mi)
        #pragma unroll
        for (int ni = 0; ni < 9; ++ni) {
            const int oc = oc0 + ni * 16 + lr;
            const int px = p0 + mi * 16 + lg * 4;
            v4us pk;
            pk[0] = f2bf(acc[mi][ni][0]); pk[1] = f2bf(acc[mi][ni][1]);
            pk[2] = f2bf(acc[mi][ni][2]); pk[3] = f2bf(acc[mi][ni][3]);
            *reinterpret_cast<v4us*>(&qkv[((size_t)bl * NOC + oc) * HW + px]) = pk;
        }
}

// ---------------- B: depthwise 3x3 + sum-of-squares ----------------
// one (bl,ch) 128x128 plane per block; q,k planes -> d_out scratch (bf16), v -> ws
__global__ __launch_bounds__(256) void k_dw(
    const u16* __restrict__ qkv, const float* __restrict__ wdw,
    u16* __restrict__ qk_out, u16* __restrict__ v_out,
    float* __restrict__ sumsq, int b0)
{
    __shared__ u16 plane[128 * 136];
    __shared__ float red[4];
    const int t = threadIdx.x;
    const int ch = blockIdx.x;
    const int bl = blockIdx.y;
    const int bg = b0 + bl;
    const size_t pbase = ((size_t)bl * NOC + ch) * HW;

    float wk[9];
    #pragma unroll
    for (int i = 0; i < 9; ++i) wk[i] = wdw[ch * 9 + i];

    const int r = t >> 1;
    const int cb = (t & 1) * 64;

    #pragma unroll
    for (int i = 0; i < 8; ++i) {
        v8us v = *reinterpret_cast<const v8us*>(&qkv[pbase + r * 128 + cb + i * 8]);
        *reinterpret_cast<v8us*>(&plane[r * 136 + cb + i * 8]) = v;
    }
    __syncthreads();

    const bool vm = (r > 0), vp = (r < 127);
    const u16* rowm = &plane[(r - 1) * 136];
    const u16* rowc = &plane[r * 136];
    const u16* rowp = &plane[(r + 1) * 136];

    float am, ac, bm, bc, cm, cc2;
    if (cb == 0) { am = 0.f; bm = 0.f; cm = 0.f; }
    else {
        am = vm ? bf2f(rowm[cb - 1]) : 0.f;
        bm = bf2f(rowc[cb - 1]);
        cm = vp ? bf2f(rowp[cb - 1]) : 0.f;
    }
    ac = vm ? bf2f(rowm[cb]) : 0.f;
    bc = bf2f(rowc[cb]);
    cc2 = vp ? bf2f(rowp[cb]) : 0.f;

    uint32_t ov[32];
    float ssq = 0.f;
    #pragma unroll
    for (int xp = 0; xp < 32; ++xp) {
        #pragma unroll
        for (int s2 = 0; s2 < 2; ++s2) {
            const int col = cb + xp * 2 + s2;
            float ap, bp, cp;
            if (col < 127) {
                ap = vm ? bf2f(rowm[col + 1]) : 0.f;
                bp = bf2f(rowc[col + 1]);
                cp = vp ? bf2f(rowp[col + 1]) : 0.f;
            } else { ap = 0.f; bp = 0.f; cp = 0.f; }
            float o = wk[0]*am + wk[1]*ac + wk[2]*ap
                    + wk[3]*bm + wk[4]*bc + wk[5]*bp
                    + wk[6]*cm + wk[7]*cc2 + wk[8]*cp;
            u16 ob = f2bf(o);
            float orr = bf2f(ob);          // consistent with what Gram/GEMM consume
            ssq += orr * orr;
            ov[xp] = (s2 == 0) ? (uint32_t)ob : (ov[xp] | ((uint32_t)ob << 16));
            am = ac; ac = ap; bm = bc; bc = bp; cm = cc2; cc2 = cp;
        }
    }

    __syncthreads();   // all neighbor reads done
    #pragma unroll
    for (int i = 0; i < 32; ++i)
        *reinterpret_cast<uint32_t*>(&plane[r * 136 + cb + i * 2]) = ov[i];
    __syncthreads();

    u16* dst = (ch < 2 * NC) ? (qk_out + ((size_t)bg * (2 * NC) + ch) * HW)
                             : (v_out + ((size_t)bg * NC + (ch - 2 * NC)) * HW);
    // 256 threads x 8 elem x 8 iters = 16384 elements
    #pragma unroll
    for (int i = 0; i < 8; ++i) {
        const int idx = i * 2048 + t * 8;
        const int rr = idx >> 7, cc = idx & 127;
        v8us v = *reinterpret_cast<const v8us*>(&plane[rr * 136 + cc]);
        *reinterpret_cast<v8us*>(&dst[idx]) = v;
    }

    #pragma unroll
    for (int off = 32; off > 0; off >>= 1) ssq += __shfl_down(ssq, off);
    if ((t & 63) == 0) red[t >> 6] = ssq;
    __syncthreads();
    if (t == 0 && ch < 2 * NC) sumsq[bg * (2 * NC) + ch] = red[0] + red[1] + red[2] + red[3];
}

// ---------------- C: partial Gram matrices q@k^T over pixel chunks ----------------
__global__ __launch_bounds__(256) void k_attn(
    const u16* __restrict__ qk, float* __restrict__ partials)
{
    __shared__ float wsum[4 * 2304];
    const int t = threadIdx.x;
    const int chunk = blockIdx.x;   // 0..15
    const int h = blockIdx.y;
    const int b = blockIdx.z;
    const int w = t >> 6, l = t & 63, lr = l & 15, lg = l >> 4;

    const size_t qbase = ((size_t)b * 384 + h * 48) * HW;
    const size_t kbase = ((size_t)b * 384 + 192 + h * 48) * HW;
    const int pb = chunk * 1024 + w * 256;

    v4f acc[3][3];
    #pragma unroll
    for (int mi = 0; mi < 3; ++mi)
        #pragma unroll
        for (int ni = 0; ni < 3; ++ni)
            acc[mi][ni] = (v4f){0.f, 0.f, 0.f, 0.f};

    #pragma unroll
    for (int ks = 0; ks < 8; ++ks) {
        const int k = pb + ks * 32 + lg * 8;
        v8bf a[3], bb[3];
        #pragma unroll
        for (int mi = 0; mi < 3; ++mi)
            a[mi] = *reinterpret_cast<const v8bf*>(&qk[qbase + (size_t)(mi * 16 + lr) * HW + k]);
        #pragma unroll
        for (int ni = 0; ni < 3; ++ni)
            bb[ni] = *reinterpret_cast<const v8bf*>(&qk[kbase + (size_t)(ni * 16 + lr) * HW + k]);
        #pragma unroll
        for (int mi = 0; mi < 3; ++mi)
            #pragma unroll
            for (int ni = 0; ni < 3; ++ni)
                acc[mi][ni] = __builtin_amdgcn_mfma_f32_16x16x32_bf16(a[mi], bb[ni], acc[mi][ni], 0, 0, 0);
    }

    #pragma unroll
    for (int mi = 0; mi < 3; ++mi)
        #pragma unroll
        for (int ni = 0; ni < 3; ++ni)
            #pragma unroll
            for (int r = 0; r < 4; ++r)
                wsum[w * 2304 + (mi * 16 + lg * 4 + r) * 48 + ni * 16 + lr] = acc[mi][ni][r];
    __syncthreads();

    #pragma unroll
    for (int i = 0; i < 9; ++i) {
        const int e = t + i * 256;
        float s = wsum[e] + wsum[2304 + e] + wsum[4608 + e] + wsum[6912 + e];
        partials[(((size_t)(b * NH + h)) * NCHUNK + chunk) * 2304 + e] = s;
    }
}

// ---------------- C2: normalize + softmax + M = Wproj @ blockdiag(attn) ----------------
// one block per (h, b): 32 blocks
__global__ __launch_bounds__(256) void k_smx(
    const float* __restrict__ partials, const float* __restrict__ sumsq,
    const float* __restrict__ wproj, const float* __restrict__ temp,
    u16* __restrict__ Mb)
{
    __shared__ float att[2304];
    __shared__ float rq[48], rk[48];
    const int t = threadIdx.x;
    const int h = blockIdx.x;
    const int b = blockIdx.y;

    if (t < 48) {
        float s = sumsq[b * 384 + h * 48 + t];
        rq[t] = 1.f / fmaxf(sqrtf(s), 1e-12f);
    } else if (t < 96) {
        float s = sumsq[b * 384 + 192 + h * 48 + (t - 48)];
        rk[t - 48] = 1.f / fmaxf(sqrtf(s), 1e-12f);
    }
    __syncthreads();
    const float tp = temp[h];
    #pragma unroll
    for (int i = 0; i < 9; ++i) {
        const int e = t + i * 256;
        const float* pp = &partials[(((size_t)(b * NH + h)) * NCHUNK) * 2304 + e];
        float s = 0.f;
        #pragma unroll
        for (int c = 0; c < NCHUNK; ++c) s += pp[(size_t)c * 2304];
        att[e] = s * rq[e / 48] * rk[e % 48] * tp;
    }
    __syncthreads();
    if (t < 48) {
        float m = -1e30f;
        #pragma unroll
        for (int j = 0; j < 48; ++j) m = fmaxf(m, att[t * 48 + j]);
        float s = 0.f;
        for (int j = 0; j < 48; ++j) { float e2 = __expf(att[t * 48 + j] - m); att[t * 48 + j] = e2; s += e2; }
        const float inv = 1.f / s;
        for (int j = 0; j < 48; ++j) att[t * 48 + j] *= inv;
    }
    __syncthreads();
    #pragma unroll
    for (int i = 0; i < 36; ++i) {
        const int idx = t + i * 256;     // 192*48 outputs
        const int oc = idx / 48, d = idx % 48;
        float s = 0.f;
        #pragma unroll
        for (int cc = 0; cc < 48; ++cc)
            s += wproj[oc * 192 + h * 48 + cc] * att[cc * 48 + d];
        Mb[((size_t)b * NC + oc) * NC + h * 48 + d] = f2bf(s);
    }
}

// ---------------- D: out[b] = M[b] @ v[b], fp32 out, swapped roles (px rows) ----------------
__global__ __launch_bounds__(256) void k_gemm_out(
    const u16* __restrict__ vp, const u16* __restrict__ Mb,
    float* __restrict__ out)
{
    __shared__ u16 bt[64 * 192];
    const int t = threadIdx.x;
    const int b = blockIdx.y;
    const int p0 = blockIdx.x * 64;

    {
        const int qp = t & 15;
        const int chw = t >> 4;
        const int px = qp * 4;
        #pragma unroll
        for (int pass = 0; pass < 12; ++pass) {
            const int ch = pass * 16 + chw;
            const v4us vv = *reinterpret_cast<const v4us*>(&vp[((size_t)b * NC + ch) * HW + p0 + px]);
            const int c4 = ch >> 3, cl = ch & 7;
            bt[(px + 0) * 192 + ((c4 ^ ((px + 0) & 7)) << 3) + cl] = vv[0];
            bt[(px + 1) * 192 + ((c4 ^ ((px + 1) & 7)) << 3) + cl] = vv[1];
            bt[(px + 2) * 192 + ((c4 ^ ((px + 2) & 7)) << 3) + cl] = vv[2];
            bt[(px + 3) * 192 + ((c4 ^ ((px + 3) & 7)) << 3) + cl] = vv[3];
        }
    }
    __syncthreads();

    const int w = t >> 6, l = t & 63, lr = l & 15, lg = l >> 4;
    const int oc0 = w * 48;                 // 4 waves x 48 oc = 192

    v4f acc[4][3];
    #pragma unroll
    for (int mi = 0; mi < 4; ++mi)
        #pragma unroll
        for (int ni = 0; ni < 3; ++ni)
            acc[mi][ni] = (v4f){0.f, 0.f, 0.f, 0.f};

    #pragma unroll
    for (int ks = 0; ks < 6; ++ks) {
        const int k = ks * 32 + lg * 8;
        const int c4 = ks * 4 + lg;
        v8bf a[4];
        #pragma unroll
        for (int mi = 0; mi < 4; ++mi) {
            const int px = mi * 16 + lr;
            a[mi] = *reinterpret_cast<const v8bf*>(&bt[px * 192 + ((c4 ^ (px & 7)) << 3)]);
        }
        #pragma unroll
        for (int ni = 0; ni < 3; ++ni) {
            const int oc = oc0 + ni * 16 + lr;
            const v8bf bw = *reinterpret_cast<const v8bf*>(&Mb[((size_t)b * NC + oc) * NC + k]);
            #pragma unroll
            for (int mi = 0; mi < 4; ++mi)
                acc[mi][ni] = __builtin_amdgcn_mfma_f32_16x16x32_bf16(a[mi], bw, acc[mi][ni], 0, 0, 0);
        }
    }

    #pragma unroll
    for (int mi = 0; mi < 4; ++mi)
        #pragma unroll
        for (int ni = 0; ni < 3; ++ni) {
            const int oc = oc0 + ni * 16 + lr;
            const int px = p0 + mi * 16 + lg * 4;
            *reinterpret_cast<v4f*>(&out[((size_t)b * NC + oc) * HW + px]) = acc[mi][ni];
        }
}

extern "C" void kernel_launch(void* const* d_in, const int* in_sizes, int n_in,
                              void* d_out, int out_size, void* d_ws, size_t ws_size,
                              hipStream_t stream)
{
    (void)in_sizes; (void)n_in; (void)out_size;
    const float* x      = (const float*)d_in[0];
    const float* f      = (const float*)d_in[1];
    const float* w_qkv  = (const float*)d_in[2];
    const float* w_dw   = (const float*)d_in[3];
    const float* w_proj = (const float*)d_in[4];
    const float* temp   = (const float*)d_in[5];

    // ws layout: fixed small stuff + v first, then adaptive qkv staging region
    char* ws = (char*)d_ws;
    u16*   vws      = (u16*)(ws);                      // 8*192*16384*2 = 50,331,648
    u16*   wb       = (u16*)(ws + 50331648);           // 576*192*2     =    221,184
    float* sumsq    = (float*)(ws + 50552832);         // 8*384*4       =     12,288
    float* partials = (float*)(ws + 50565120);         // 8*4*16*2304*4 =  4,718,592
    u16*   Mb       = (u16*)(ws + 55283712);           // 8*192*192*2   =    589,824
    const size_t FIXED = 55873536;
    const size_t PERB  = (size_t)NOC * HW * 2;         // 18,874,368 per batch
    u16*   qkv_raw  = (u16*)(ws + FIXED);

    int g = 1;
    if (ws_size > FIXED + PERB) {
        size_t avail = (ws_size - FIXED) / PERB;
        g = (int)(avail > 8 ? 8 : avail);
        if (g < 1) g = 1;
    }

    u16* qk_scratch = (u16*)d_out;   // q,k planes (bf16) — exactly fills d_out, consumed before final GEMM
    float* out      = (float*)d_out;

    hipLaunchKernelGGL(k_cvt_w, dim3(432), dim3(256), 0, stream, w_qkv, wb, NOC * NC);
    for (int b0 = 0; b0 < NB; b0 += g) {
        const int nb = (b0 + g <= NB) ? g : (NB - b0);
        hipLaunchKernelGGL(k_gemm_qkv, dim3(HW / 64, nb), dim3(256), 0, stream, x, f, wb, qkv_raw, b0);
        hipLaunchKernelGGL(k_dw, dim3(NOC, nb), dim3(256), 0, stream, qkv_raw, w_dw, qk_scratch, vws, sumsq, b0);
    }
    hipLaunchKernelGGL(k_attn, dim3(NCHUNK, NH, NB), dim3(256), 0, stream, qk_scratch, partials);
    hipLaunchKernelGGL(k_smx, dim3(NH, NB), dim3(256), 0, stream, partials, sumsq, w_proj, temp, Mb);
    hipLaunchKernelGGL(k_gemm_out, dim3(HW / 64, NB), dim3(256), 0, stream, vws, Mb, out);
}

// Round 5
// 333.512 us; speedup vs baseline: 1.7757x; 1.0649x over previous
//
#include <hip/hip_runtime.h>
#include <stdint.h>

#define NB 8
#define NC 192
#define NOC 576
#define NH 4
#define HW 16384
#define NCHUNK 16

typedef unsigned short u16;
typedef __bf16 v8bf __attribute__((ext_vector_type(8)));
typedef float v4f __attribute__((ext_vector_type(4)));
typedef u16 v8us __attribute__((ext_vector_type(8)));
typedef u16 v4us __attribute__((ext_vector_type(4)));

__device__ __forceinline__ u16 f2bf(float f) {
    uint32_t u = __float_as_uint(f);
    u += 0x7FFFu + ((u >> 16) & 1u);
    return (u16)(u >> 16);
}
__device__ __forceinline__ float bf2f(u16 u) {
    return __uint_as_float(((uint32_t)u) << 16);
}

// ---------------- P: convert w_qkv to bf16 ----------------
__global__ void k_cvt_w(const float* __restrict__ w, u16* __restrict__ wb, int n) {
    int i = blockIdx.x * 256 + threadIdx.x;
    if (i < n) wb[i] = f2bf(w[i]);
}

// ---------------- A: qkv_raw[bl][oc][p] = W[oc][c] @ (x+f)[b0+bl][c][p] ----------------
// D rows = pixels, D cols = oc. 64 px staged in LDS (swizzled, conflict-free);
// W K-chunks (576x32) cooperatively staged in LDS per K-step.
__global__ __launch_bounds__(256, 2) void k_gemm_qkv(
    const float* __restrict__ x, const float* __restrict__ f,
    const u16* __restrict__ wb, u16* __restrict__ qkv, int b0)
{
    __shared__ u16 bt[64 * 192];    // 24576 B  [px][ch chunks, XOR swizzled]
    __shared__ u16 wt[576 * 32];    // 36864 B  [oc][k chunk, XOR swizzled]
    const int t = threadIdx.x;
    const int bl = blockIdx.y;
    const int bg = b0 + bl;
    const int p0 = blockIdx.x * 64;

    // stage x+f: 64 px x 192 ch. Scalar coalesced loads (256B/instr), packed b128 LDS writes.
    {
        const int px = t & 63;
        const int cg = t >> 6;              // 0..3
        #pragma unroll
        for (int it = 0; it < 6; ++it) {
            const int c4 = it * 4 + cg;     // 0..23
            const size_t base = ((size_t)bg * NC + c4 * 8) * HW + p0 + px;
            v8us pk;
            #pragma unroll
            for (int j = 0; j < 8; ++j) {
                float v = x[base + (size_t)j * HW] + f[base + (size_t)j * HW];
                pk[j] = f2bf(v);
            }
            *reinterpret_cast<v8us*>(&bt[px * 192 + ((c4 ^ (px & 7)) << 3)]) = pk;
        }
    }

    const int w = t >> 6, l = t & 63, lr = l & 15, lg = l >> 4;
    const int oc0 = w * 144;                 // 4 waves x 144 oc = 576

    v4f acc[4][9];
    #pragma unroll
    for (int mi = 0; mi < 4; ++mi)
        #pragma unroll
        for (int ni = 0; ni < 9; ++ni)
            acc[mi][ni] = (v4f){0.f, 0.f, 0.f, 0.f};

    #pragma unroll 1
    for (int ks = 0; ks < 6; ++ks) {
        __syncthreads();   // prev chunk fully consumed (also orders bt staging on ks=0)
        // cooperative stage of W[:, ks*32 .. ks*32+32): 2304 x 16B chunks
        #pragma unroll
        for (int it = 0; it < 9; ++it) {
            const int idx = it * 256 + t;
            const int oc = idx >> 2, lgw = idx & 3;
            v8us wv = *reinterpret_cast<const v8us*>(&wb[oc * 192 + ks * 32 + lgw * 8]);
            *reinterpret_cast<v8us*>(&wt[oc * 32 + ((lgw ^ ((oc >> 1) & 3)) << 3)]) = wv;
        }
        __syncthreads();

        v8bf a[4];
        #pragma unroll
        for (int mi = 0; mi < 4; ++mi) {
            const int px = mi * 16 + lr;
            a[mi] = *reinterpret_cast<const v8bf*>(&bt[px * 192 + (((ks * 4 + lg) ^ (px & 7)) << 3)]);
        }
        #pragma unroll
        for (int ni = 0; ni < 9; ++ni) {
            const int oc = oc0 + ni * 16 + lr;
            const v8bf bw = *reinterpret_cast<const v8bf*>(&wt[oc * 32 + ((lg ^ ((oc >> 1) & 3)) << 3)]);
            #pragma unroll
            for (int mi = 0; mi < 4; ++mi)
                acc[mi][ni] = __builtin_amdgcn_mfma_f32_16x16x32_bf16(a[mi], bw, acc[mi][ni], 0, 0, 0);
        }
    }

    #pragma unroll
    for (int mi = 0; mi < 4; ++mi)
        #pragma unroll
        for (int ni = 0; ni < 9; ++ni) {
            const int oc = oc0 + ni * 16 + lr;
            const int px = p0 + mi * 16 + lg * 4;
            v4us pk;
            pk[0] = f2bf(acc[mi][ni][0]); pk[1] = f2bf(acc[mi][ni][1]);
            pk[2] = f2bf(acc[mi][ni][2]); pk[3] = f2bf(acc[mi][ni][3]);
            *reinterpret_cast<v4us*>(&qkv[((size_t)bl * NOC + oc) * HW + px]) = pk;
        }
}

// ---------------- B: depthwise 3x3 + sum-of-squares ----------------
// one (bl,ch) 128x128 plane per block; q,k planes -> d_out scratch (bf16), v -> ws
__global__ __launch_bounds__(256) void k_dw(
    const u16* __restrict__ qkv, const float* __restrict__ wdw,
    u16* __restrict__ qk_out, u16* __restrict__ v_out,
    float* __restrict__ sumsq, int b0)
{
    __shared__ u16 plane[128 * 136];
    __shared__ float red[4];
    const int t = threadIdx.x;
    const int ch = blockIdx.x;
    const int bl = blockIdx.y;
    const int bg = b0 + bl;
    const size_t pbase = ((size_t)bl * NOC + ch) * HW;

    float wk[9];
    #pragma unroll
    for (int i = 0; i < 9; ++i) wk[i] = wdw[ch * 9 + i];

    const int r = t >> 1;
    const int cb = (t & 1) * 64;

    #pragma unroll
    for (int i = 0; i < 8; ++i) {
        v8us v = *reinterpret_cast<const v8us*>(&qkv[pbase + r * 128 + cb + i * 8]);
        *reinterpret_cast<v8us*>(&plane[r * 136 + cb + i * 8]) = v;
    }
    __syncthreads();

    const bool vm = (r > 0), vp = (r < 127);
    const u16* rowm = &plane[(r - 1) * 136];
    const u16* rowc = &plane[r * 136];
    const u16* rowp = &plane[(r + 1) * 136];

    float am, ac, bm, bc, cm, cc2;
    if (cb == 0) { am = 0.f; bm = 0.f; cm = 0.f; }
    else {
        am = vm ? bf2f(rowm[cb - 1]) : 0.f;
        bm = bf2f(rowc[cb - 1]);
        cm = vp ? bf2f(rowp[cb - 1]) : 0.f;
    }
    ac = vm ? bf2f(rowm[cb]) : 0.f;
    bc = bf2f(rowc[cb]);
    cc2 = vp ? bf2f(rowp[cb]) : 0.f;

    uint32_t ov[32];
    float ssq = 0.f;
    #pragma unroll
    for (int xp = 0; xp < 32; ++xp) {
        #pragma unroll
        for (int s2 = 0; s2 < 2; ++s2) {
            const int col = cb + xp * 2 + s2;
            float ap, bp, cp;
            if (col < 127) {
                ap = vm ? bf2f(rowm[col + 1]) : 0.f;
                bp = bf2f(rowc[col + 1]);
                cp = vp ? bf2f(rowp[col + 1]) : 0.f;
            } else { ap = 0.f; bp = 0.f; cp = 0.f; }
            float o = wk[0]*am + wk[1]*ac + wk[2]*ap
                    + wk[3]*bm + wk[4]*bc + wk[5]*bp
                    + wk[6]*cm + wk[7]*cc2 + wk[8]*cp;
            u16 ob = f2bf(o);
            float orr = bf2f(ob);          // consistent with what Gram/GEMM consume
            ssq += orr * orr;
            ov[xp] = (s2 == 0) ? (uint32_t)ob : (ov[xp] | ((uint32_t)ob << 16));
            am = ac; ac = ap; bm = bc; bc = bp; cm = cc2; cc2 = cp;
        }
    }

    __syncthreads();   // all neighbor reads done
    #pragma unroll
    for (int i = 0; i < 32; ++i)
        *reinterpret_cast<uint32_t*>(&plane[r * 136 + cb + i * 2]) = ov[i];
    __syncthreads();

    u16* dst = (ch < 2 * NC) ? (qk_out + ((size_t)bg * (2 * NC) + ch) * HW)
                             : (v_out + ((size_t)bg * NC + (ch - 2 * NC)) * HW);
    // 256 threads x 8 elem x 8 iters = 16384 elements
    #pragma unroll
    for (int i = 0; i < 8; ++i) {
        const int idx = i * 2048 + t * 8;
        const int rr = idx >> 7, cc = idx & 127;
        v8us v = *reinterpret_cast<const v8us*>(&plane[rr * 136 + cc]);
        *reinterpret_cast<v8us*>(&dst[idx]) = v;
    }

    #pragma unroll
    for (int off = 32; off > 0; off >>= 1) ssq += __shfl_down(ssq, off);
    if ((t & 63) == 0) red[t >> 6] = ssq;
    __syncthreads();
    if (t == 0 && ch < 2 * NC) sumsq[bg * (2 * NC) + ch] = red[0] + red[1] + red[2] + red[3];
}

// ---------------- C: partial Gram matrices q@k^T over pixel chunks ----------------
__global__ __launch_bounds__(256) void k_attn(
    const u16* __restrict__ qk, float* __restrict__ partials)
{
    __shared__ float wsum[4 * 2304];
    const int t = threadIdx.x;
    const int chunk = blockIdx.x;   // 0..15
    const int h = blockIdx.y;
    const int b = blockIdx.z;
    const int w = t >> 6, l = t & 63, lr = l & 15, lg = l >> 4;

    const size_t qbase = ((size_t)b * 384 + h * 48) * HW;
    const size_t kbase = ((size_t)b * 384 + 192 + h * 48) * HW;
    const int pb = chunk * 1024 + w * 256;

    v4f acc[3][3];
    #pragma unroll
    for (int mi = 0; mi < 3; ++mi)
        #pragma unroll
        for (int ni = 0; ni < 3; ++ni)
            acc[mi][ni] = (v4f){0.f, 0.f, 0.f, 0.f};

    #pragma unroll
    for (int ks = 0; ks < 8; ++ks) {
        const int k = pb + ks * 32 + lg * 8;
        v8bf a[3], bb[3];
        #pragma unroll
        for (int mi = 0; mi < 3; ++mi)
            a[mi] = *reinterpret_cast<const v8bf*>(&qk[qbase + (size_t)(mi * 16 + lr) * HW + k]);
        #pragma unroll
        for (int ni = 0; ni < 3; ++ni)
            bb[ni] = *reinterpret_cast<const v8bf*>(&qk[kbase + (size_t)(ni * 16 + lr) * HW + k]);
        #pragma unroll
        for (int mi = 0; mi < 3; ++mi)
            #pragma unroll
            for (int ni = 0; ni < 3; ++ni)
                acc[mi][ni] = __builtin_amdgcn_mfma_f32_16x16x32_bf16(a[mi], bb[ni], acc[mi][ni], 0, 0, 0);
    }

    #pragma unroll
    for (int mi = 0; mi < 3; ++mi)
        #pragma unroll
        for (int ni = 0; ni < 3; ++ni)
            #pragma unroll
            for (int r = 0; r < 4; ++r)
                wsum[w * 2304 + (mi * 16 + lg * 4 + r) * 48 + ni * 16 + lr] = acc[mi][ni][r];
    __syncthreads();

    #pragma unroll
    for (int i = 0; i < 9; ++i) {
        const int e = t + i * 256;
        float s = wsum[e] + wsum[2304 + e] + wsum[4608 + e] + wsum[6912 + e];
        partials[(((size_t)(b * NH + h)) * NCHUNK + chunk) * 2304 + e] = s;
    }
}

// ---------------- C2: normalize + softmax + M = Wproj @ blockdiag(attn) ----------------
// one block per (h, b): 32 blocks
__global__ __launch_bounds__(256) void k_smx(
    const float* __restrict__ partials, const float* __restrict__ sumsq,
    const float* __restrict__ wproj, const float* __restrict__ temp,
    u16* __restrict__ Mb)
{
    __shared__ float att[2304];
    __shared__ float rq[48], rk[48];
    const int t = threadIdx.x;
    const int h = blockIdx.x;
    const int b = blockIdx.y;

    if (t < 48) {
        float s = sumsq[b * 384 + h * 48 + t];
        rq[t] = 1.f / fmaxf(sqrtf(s), 1e-12f);
    } else if (t < 96) {
        float s = sumsq[b * 384 + 192 + h * 48 + (t - 48)];
        rk[t - 48] = 1.f / fmaxf(sqrtf(s), 1e-12f);
    }
    __syncthreads();
    const float tp = temp[h];
    #pragma unroll
    for (int i = 0; i < 9; ++i) {
        const int e = t + i * 256;
        const float* pp = &partials[(((size_t)(b * NH + h)) * NCHUNK) * 2304 + e];
        float s = 0.f;
        #pragma unroll
        for (int c = 0; c < NCHUNK; ++c) s += pp[(size_t)c * 2304];
        att[e] = s * rq[e / 48] * rk[e % 48] * tp;
    }
    __syncthreads();
    if (t < 48) {
        float m = -1e30f;
        #pragma unroll
        for (int j = 0; j < 48; ++j) m = fmaxf(m, att[t * 48 + j]);
        float s = 0.f;
        for (int j = 0; j < 48; ++j) { float e2 = __expf(att[t * 48 + j] - m); att[t * 48 + j] = e2; s += e2; }
        const float inv = 1.f / s;
        for (int j = 0; j < 48; ++j) att[t * 48 + j] *= inv;
    }
    __syncthreads();
    #pragma unroll
    for (int i = 0; i < 36; ++i) {
        const int idx = t + i * 256;     // 192*48 outputs
        const int oc = idx / 48, d = idx % 48;
        float s = 0.f;
        #pragma unroll
        for (int cc = 0; cc < 48; ++cc)
            s += wproj[oc * 192 + h * 48 + cc] * att[cc * 48 + d];
        Mb[((size_t)b * NC + oc) * NC + h * 48 + d] = f2bf(s);
    }
}

// ---------------- D: out[b] = M[b] @ v[b], fp32 out, px rows ----------------
__global__ __launch_bounds__(256) void k_gemm_out(
    const u16* __restrict__ vp, const u16* __restrict__ Mb,
    float* __restrict__ out)
{
    __shared__ u16 bt[64 * 192];
    const int t = threadIdx.x;
    const int b = blockIdx.y;
    const int p0 = blockIdx.x * 64;

    {
        const int px = t & 63;
        const int cg = t >> 6;              // 0..3
        #pragma unroll
        for (int it = 0; it < 6; ++it) {
            const int c4 = it * 4 + cg;     // 0..23
            const size_t base = ((size_t)b * NC + c4 * 8) * HW + p0 + px;
            v8us pk;
            #pragma unroll
            for (int j = 0; j < 8; ++j) pk[j] = vp[base + (size_t)j * HW];
            *reinterpret_cast<v8us*>(&bt[px * 192 + ((c4 ^ (px & 7)) << 3)]) = pk;
        }
    }
    __syncthreads();

    const int w = t >> 6, l = t & 63, lr = l & 15, lg = l >> 4;
    const int oc0 = w * 48;                 // 4 waves x 48 oc = 192

    v4f acc[4][3];
    #pragma unroll
    for (int mi = 0; mi < 4; ++mi)
        #pragma unroll
        for (int ni = 0; ni < 3; ++ni)
            acc[mi][ni] = (v4f){0.f, 0.f, 0.f, 0.f};

    #pragma unroll
    for (int ks = 0; ks < 6; ++ks) {
        const int k = ks * 32 + lg * 8;
        const int c4 = ks * 4 + lg;
        v8bf a[4];
        #pragma unroll
        for (int mi = 0; mi < 4; ++mi) {
            const int px = mi * 16 + lr;
            a[mi] = *reinterpret_cast<const v8bf*>(&bt[px * 192 + ((c4 ^ (px & 7)) << 3)]);
        }
        #pragma unroll
        for (int ni = 0; ni < 3; ++ni) {
            const int oc = oc0 + ni * 16 + lr;
            const v8bf bw = *reinterpret_cast<const v8bf*>(&Mb[((size_t)b * NC + oc) * NC + k]);
            #pragma unroll
            for (int mi = 0; mi < 4; ++mi)
                acc[mi][ni] = __builtin_amdgcn_mfma_f32_16x16x32_bf16(a[mi], bw, acc[mi][ni], 0, 0, 0);
        }
    }

    #pragma unroll
    for (int mi = 0; mi < 4; ++mi)
        #pragma unroll
        for (int ni = 0; ni < 3; ++ni) {
            const int oc = oc0 + ni * 16 + lr;
            const int px = p0 + mi * 16 + lg * 4;
            *reinterpret_cast<v4f*>(&out[((size_t)b * NC + oc) * HW + px]) = acc[mi][ni];
        }
}

extern "C" void kernel_launch(void* const* d_in, const int* in_sizes, int n_in,
                              void* d_out, int out_size, void* d_ws, size_t ws_size,
                              hipStream_t stream)
{
    (void)in_sizes; (void)n_in; (void)out_size;
    const float* x      = (const float*)d_in[0];
    const float* f      = (const float*)d_in[1];
    const float* w_qkv  = (const float*)d_in[2];
    const float* w_dw   = (const float*)d_in[3];
    const float* w_proj = (const float*)d_in[4];
    const float* temp   = (const float*)d_in[5];

    // ws layout: fixed small stuff + v first, then adaptive qkv staging region
    char* ws = (char*)d_ws;
    u16*   vws      = (u16*)(ws);                      // 8*192*16384*2 = 50,331,648
    u16*   wb       = (u16*)(ws + 50331648);           // 576*192*2     =    221,184
    float* sumsq    = (float*)(ws + 50552832);         // 8*384*4       =     12,288
    float* partials = (float*)(ws + 50565120);         // 8*4*16*2304*4 =  4,718,592
    u16*   Mb       = (u16*)(ws + 55283712);           // 8*192*192*2   =    589,824
    const size_t FIXED = 55873536;
    const size_t PERB  = (size_t)NOC * HW * 2;         // 18,874,368 per batch
    u16*   qkv_raw  = (u16*)(ws + FIXED);

    int g = 1;
    if (ws_size > FIXED + PERB) {
        size_t avail = (ws_size - FIXED) / PERB;
        g = (int)(avail > 8 ? 8 : avail);
        if (g < 1) g = 1;
    }

    u16* qk_scratch = (u16*)d_out;   // q,k planes (bf16) — exactly fills d_out, consumed before final GEMM
    float* out      = (float*)d_out;

    hipLaunchKernelGGL(k_cvt_w, dim3(432), dim3(256), 0, stream, w_qkv, wb, NOC * NC);
    for (int b0 = 0; b0 < NB; b0 += g) {
        const int nb = (b0 + g <= NB) ? g : (NB - b0);
        hipLaunchKernelGGL(k_gemm_qkv, dim3(HW / 64, nb), dim3(256), 0, stream, x, f, wb, qkv_raw, b0);
        hipLaunchKernelGGL(k_dw, dim3(NOC, nb), dim3(256), 0, stream, qkv_raw, w_dw, qk_scratch, vws, sumsq, b0);
    }
    hipLaunchKernelGGL(k_attn, dim3(NCHUNK, NH, NB), dim3(256), 0, stream, qk_scratch, partials);
    hipLaunchKernelGGL(k_smx, dim3(NH, NB), dim3(256), 0, stream, partials, sumsq, w_proj, temp, Mb);
    hipLaunchKernelGGL(k_gemm_out, dim3(HW / 64, NB), dim3(256), 0, stream, vws, Mb, out);
}

// Round 6
// 309.963 us; speedup vs baseline: 1.9106x; 1.0760x over previous
//
#include <hip/hip_runtime.h>
#include <stdint.h>

#define NB 8
#define NC 192
#define NOC 576
#define NH 4
#define HW 16384
#define NCHUNK 16

typedef unsigned short u16;
typedef __bf16 v8bf __attribute__((ext_vector_type(8)));
typedef float v4f __attribute__((ext_vector_type(4)));
typedef u16 v8us __attribute__((ext_vector_type(8)));
typedef u16 v4us __attribute__((ext_vector_type(4)));

__device__ __forceinline__ u16 f2bf(float f) {
    uint32_t u = __float_as_uint(f);
    u += 0x7FFFu + ((u >> 16) & 1u);
    return (u16)(u >> 16);
}
__device__ __forceinline__ float bf2f(u16 u) {
    return __uint_as_float(((uint32_t)u) << 16);
}

// ---------------- P: convert w_qkv to bf16 ----------------
__global__ void k_cvt_w(const float* __restrict__ w, u16* __restrict__ wb, int n) {
    int i = blockIdx.x * 256 + threadIdx.x;
    if (i < n) wb[i] = f2bf(w[i]);
}

// ---------------- A: qkv_raw[bl][oc][p] = W[oc][c] @ (x+f)[b0+bl][c][p] ----------------
// D rows = pixels, D cols = oc. 64 px staged in LDS (swizzled, conflict-free);
// W K-chunks (576x32) double-buffered via registers -> LDS per K-step.
// Epilogue: C tile round-trips LDS so each global store is a full 64B-aligned run.
__global__ __launch_bounds__(256, 2) void k_gemm_qkv(
    const float* __restrict__ x, const float* __restrict__ f,
    const u16* __restrict__ wb, u16* __restrict__ qkv, int b0)
{
    __shared__ u16 bt[64 * 192];    // 24576 B  [px][ch chunks, XOR swizzled]
    __shared__ u16 wt[576 * 32];    // 36864 B  [oc][k chunk, XOR swizzled] / epilogue C tile
    const int t = threadIdx.x;
    const int bl = blockIdx.y;
    const int bg = b0 + bl;
    const int p0 = blockIdx.x * 64;

    // stage x+f: 64 px x 192 ch. Scalar coalesced loads (256B/instr), packed b128 LDS writes.
    {
        const int px = t & 63;
        const int cg = t >> 6;              // 0..3
        #pragma unroll
        for (int it = 0; it < 6; ++it) {
            const int c4 = it * 4 + cg;     // 0..23
            const size_t base = ((size_t)bg * NC + c4 * 8) * HW + p0 + px;
            v8us pk;
            #pragma unroll
            for (int j = 0; j < 8; ++j) {
                float v = x[base + (size_t)j * HW] + f[base + (size_t)j * HW];
                pk[j] = f2bf(v);
            }
            *reinterpret_cast<v8us*>(&bt[px * 192 + ((c4 ^ (px & 7)) << 3)]) = pk;
        }
    }

    const int w = t >> 6, l = t & 63, lr = l & 15, lg = l >> 4;
    const int oc0 = w * 144;                 // 4 waves x 144 oc = 576

    v4f acc[4][9];
    #pragma unroll
    for (int mi = 0; mi < 4; ++mi)
        #pragma unroll
        for (int ni = 0; ni < 9; ++ni)
            acc[mi][ni] = (v4f){0.f, 0.f, 0.f, 0.f};

    const int widx_oc = (t * 4) >> 2;        // placeholder (kept simple below)

    // prologue: prefetch W chunk 0 into registers
    v8us wload[9];
    #pragma unroll
    for (int it = 0; it < 9; ++it) {
        const int idx = it * 256 + t;
        const int oc = idx >> 2, lgw = idx & 3;
        wload[it] = *reinterpret_cast<const v8us*>(&wb[oc * 192 + lgw * 8]);
    }

    #pragma unroll 1
    for (int ks = 0; ks < 6; ++ks) {
        __syncthreads();   // prev chunk fully consumed (also orders bt staging on ks=0)
        // commit prefetched W chunk to LDS
        #pragma unroll
        for (int it = 0; it < 9; ++it) {
            const int idx = it * 256 + t;
            const int oc = idx >> 2, lgw = idx & 3;
            *reinterpret_cast<v8us*>(&wt[oc * 32 + ((lgw ^ ((oc >> 1) & 3)) << 3)]) = wload[it];
        }
        // prefetch next chunk (flies under barrier + MFMA)
        if (ks < 5) {
            #pragma unroll
            for (int it = 0; it < 9; ++it) {
                const int idx = it * 256 + t;
                const int oc = idx >> 2, lgw = idx & 3;
                wload[it] = *reinterpret_cast<const v8us*>(&wb[oc * 192 + (ks + 1) * 32 + lgw * 8]);
            }
        }
        __syncthreads();

        v8bf a[4];
        #pragma unroll
        for (int mi = 0; mi < 4; ++mi) {
            const int px = mi * 16 + lr;
            a[mi] = *reinterpret_cast<const v8bf*>(&bt[px * 192 + (((ks * 4 + lg) ^ (px & 7)) << 3)]);
        }
        #pragma unroll
        for (int ni = 0; ni < 9; ++ni) {
            const int oc = oc0 + ni * 16 + lr;
            const v8bf bw = *reinterpret_cast<const v8bf*>(&wt[oc * 32 + ((lg ^ ((oc >> 1) & 3)) << 3)]);
            #pragma unroll
            for (int mi = 0; mi < 4; ++mi)
                acc[mi][ni] = __builtin_amdgcn_mfma_f32_16x16x32_bf16(a[mi], bw, acc[mi][ni], 0, 0, 0);
        }
    }

    // ---- epilogue: two passes of [576 oc][32 px] through wt, full-64B-run global stores ----
    #pragma unroll
    for (int pass = 0; pass < 2; ++pass) {
        __syncthreads();   // wt (or prev pass tile) fully consumed
        #pragma unroll
        for (int mi2 = 0; mi2 < 2; ++mi2) {
            const int mi = pass * 2 + mi2;
            #pragma unroll
            for (int ni = 0; ni < 9; ++ni) {
                const int oc = oc0 + ni * 16 + lr;
                const int chunk = mi2 * 4 + lg;          // 4-px chunk 0..7 within 32 px
                const int sch = chunk ^ (oc & 3);        // bank swizzle
                v4us pk;
                pk[0] = f2bf(acc[mi][ni][0]); pk[1] = f2bf(acc[mi][ni][1]);
                pk[2] = f2bf(acc[mi][ni][2]); pk[3] = f2bf(acc[mi][ni][3]);
                *reinterpret_cast<v4us*>(&wt[oc * 32 + sch * 4]) = pk;
            }
        }
        __syncthreads();
        // 576 rows x 32 px: 9 rounds x 256 threads x 8 u16. 4 lanes/row -> 64B aligned runs.
        #pragma unroll
        for (int rd = 0; rd < 9; ++rd) {
            const int e = rd * 2048 + t * 8;
            const int oc = e >> 5;
            const int col = e & 31;                      // 0,8,16,24
            const int c0 = (col >> 2) ^ (oc & 3);
            const int c1 = ((col >> 2) + 1) ^ (oc & 3);
            v4us lo = *reinterpret_cast<v4us*>(&wt[oc * 32 + c0 * 4]);
            v4us hi = *reinterpret_cast<v4us*>(&wt[oc * 32 + c1 * 4]);
            v8us o8;
            o8[0] = lo[0]; o8[1] = lo[1]; o8[2] = lo[2]; o8[3] = lo[3];
            o8[4] = hi[0]; o8[5] = hi[1]; o8[6] = hi[2]; o8[7] = hi[3];
            *reinterpret_cast<v8us*>(&qkv[((size_t)bl * NOC + oc) * HW + p0 + pass * 32 + col]) = o8;
        }
    }
    (void)widx_oc;
}

// ---------------- B: depthwise 3x3 + sum-of-squares ----------------
// one (bl,ch) 128x128 plane per block; q,k planes -> d_out scratch (bf16), v -> ws
__global__ __launch_bounds__(256) void k_dw(
    const u16* __restrict__ qkv, const float* __restrict__ wdw,
    u16* __restrict__ qk_out, u16* __restrict__ v_out,
    float* __restrict__ sumsq, int b0)
{
    __shared__ u16 plane[128 * 136];
    __shared__ float red[4];
    const int t = threadIdx.x;
    const int ch = blockIdx.x;
    const int bl = blockIdx.y;
    const int bg = b0 + bl;
    const size_t pbase = ((size_t)bl * NOC + ch) * HW;

    float wk[9];
    #pragma unroll
    for (int i = 0; i < 9; ++i) wk[i] = wdw[ch * 9 + i];

    const int r = t >> 1;
    const int cb = (t & 1) * 64;

    #pragma unroll
    for (int i = 0; i < 8; ++i) {
        v8us v = *reinterpret_cast<const v8us*>(&qkv[pbase + r * 128 + cb + i * 8]);
        *reinterpret_cast<v8us*>(&plane[r * 136 + cb + i * 8]) = v;
    }
    __syncthreads();

    const bool vm = (r > 0), vp = (r < 127);
    const u16* rowm = &plane[(r - 1) * 136];
    const u16* rowc = &plane[r * 136];
    const u16* rowp = &plane[(r + 1) * 136];

    float am, ac, bm, bc, cm, cc2;
    if (cb == 0) { am = 0.f; bm = 0.f; cm = 0.f; }
    else {
        am = vm ? bf2f(rowm[cb - 1]) : 0.f;
        bm = bf2f(rowc[cb - 1]);
        cm = vp ? bf2f(rowp[cb - 1]) : 0.f;
    }
    ac = vm ? bf2f(rowm[cb]) : 0.f;
    bc = bf2f(rowc[cb]);
    cc2 = vp ? bf2f(rowp[cb]) : 0.f;

    uint32_t ov[32];
    float ssq = 0.f;
    #pragma unroll
    for (int xp = 0; xp < 32; ++xp) {
        #pragma unroll
        for (int s2 = 0; s2 < 2; ++s2) {
            const int col = cb + xp * 2 + s2;
            float ap, bp, cp;
            if (col < 127) {
                ap = vm ? bf2f(rowm[col + 1]) : 0.f;
                bp = bf2f(rowc[col + 1]);
                cp = vp ? bf2f(rowp[col + 1]) : 0.f;
            } else { ap = 0.f; bp = 0.f; cp = 0.f; }
            float o = wk[0]*am + wk[1]*ac + wk[2]*ap
                    + wk[3]*bm + wk[4]*bc + wk[5]*bp
                    + wk[6]*cm + wk[7]*cc2 + wk[8]*cp;
            u16 ob = f2bf(o);
            float orr = bf2f(ob);          // consistent with what Gram/GEMM consume
            ssq += orr * orr;
            ov[xp] = (s2 == 0) ? (uint32_t)ob : (ov[xp] | ((uint32_t)ob << 16));
            am = ac; ac = ap; bm = bc; bc = bp; cm = cc2; cc2 = cp;
        }
    }

    __syncthreads();   // all neighbor reads done
    #pragma unroll
    for (int i = 0; i < 32; ++i)
        *reinterpret_cast<uint32_t*>(&plane[r * 136 + cb + i * 2]) = ov[i];
    __syncthreads();

    u16* dst = (ch < 2 * NC) ? (qk_out + ((size_t)bg * (2 * NC) + ch) * HW)
                             : (v_out + ((size_t)bg * NC + (ch - 2 * NC)) * HW);
    // 256 threads x 8 elem x 8 iters = 16384 elements
    #pragma unroll
    for (int i = 0; i < 8; ++i) {
        const int idx = i * 2048 + t * 8;
        const int rr = idx >> 7, cc = idx & 127;
        v8us v = *reinterpret_cast<const v8us*>(&plane[rr * 136 + cc]);
        *reinterpret_cast<v8us*>(&dst[idx]) = v;
    }

    #pragma unroll
    for (int off = 32; off > 0; off >>= 1) ssq += __shfl_down(ssq, off);
    if ((t & 63) == 0) red[t >> 6] = ssq;
    __syncthreads();
    if (t == 0 && ch < 2 * NC) sumsq[bg * (2 * NC) + ch] = red[0] + red[1] + red[2] + red[3];
}

// ---------------- C: partial Gram matrices q@k^T over pixel chunks ----------------
__global__ __launch_bounds__(256) void k_attn(
    const u16* __restrict__ qk, float* __restrict__ partials)
{
    __shared__ float wsum[4 * 2304];
    const int t = threadIdx.x;
    const int chunk = blockIdx.x;   // 0..15
    const int h = blockIdx.y;
    const int b = blockIdx.z;
    const int w = t >> 6, l = t & 63, lr = l & 15, lg = l >> 4;

    const size_t qbase = ((size_t)b * 384 + h * 48) * HW;
    const size_t kbase = ((size_t)b * 384 + 192 + h * 48) * HW;
    const int pb = chunk * 1024 + w * 256;

    v4f acc[3][3];
    #pragma unroll
    for (int mi = 0; mi < 3; ++mi)
        #pragma unroll
        for (int ni = 0; ni < 3; ++ni)
            acc[mi][ni] = (v4f){0.f, 0.f, 0.f, 0.f};

    #pragma unroll
    for (int ks = 0; ks < 8; ++ks) {
        const int k = pb + ks * 32 + lg * 8;
        v8bf a[3], bb[3];
        #pragma unroll
        for (int mi = 0; mi < 3; ++mi)
            a[mi] = *reinterpret_cast<const v8bf*>(&qk[qbase + (size_t)(mi * 16 + lr) * HW + k]);
        #pragma unroll
        for (int ni = 0; ni < 3; ++ni)
            bb[ni] = *reinterpret_cast<const v8bf*>(&qk[kbase + (size_t)(ni * 16 + lr) * HW + k]);
        #pragma unroll
        for (int mi = 0; mi < 3; ++mi)
            #pragma unroll
            for (int ni = 0; ni < 3; ++ni)
                acc[mi][ni] = __builtin_amdgcn_mfma_f32_16x16x32_bf16(a[mi], bb[ni], acc[mi][ni], 0, 0, 0);
    }

    #pragma unroll
    for (int mi = 0; mi < 3; ++mi)
        #pragma unroll
        for (int ni = 0; ni < 3; ++ni)
            #pragma unroll
            for (int r = 0; r < 4; ++r)
                wsum[w * 2304 + (mi * 16 + lg * 4 + r) * 48 + ni * 16 + lr] = acc[mi][ni][r];
    __syncthreads();

    #pragma unroll
    for (int i = 0; i < 9; ++i) {
        const int e = t + i * 256;
        float s = wsum[e] + wsum[2304 + e] + wsum[4608 + e] + wsum[6912 + e];
        partials[(((size_t)(b * NH + h)) * NCHUNK + chunk) * 2304 + e] = s;
    }
}

// ---------------- C2: normalize + softmax + M = Wproj @ blockdiag(attn) ----------------
// one block per (h, b): 32 blocks
__global__ __launch_bounds__(256) void k_smx(
    const float* __restrict__ partials, const float* __restrict__ sumsq,
    const float* __restrict__ wproj, const float* __restrict__ temp,
    u16* __restrict__ Mb)
{
    __shared__ float att[2304];
    __shared__ float rq[48], rk[48];
    const int t = threadIdx.x;
    const int h = blockIdx.x;
    const int b = blockIdx.y;

    if (t < 48) {
        float s = sumsq[b * 384 + h * 48 + t];
        rq[t] = 1.f / fmaxf(sqrtf(s), 1e-12f);
    } else if (t < 96) {
        float s = sumsq[b * 384 + 192 + h * 48 + (t - 48)];
        rk[t - 48] = 1.f / fmaxf(sqrtf(s), 1e-12f);
    }
    __syncthreads();
    const float tp = temp[h];
    #pragma unroll
    for (int i = 0; i < 9; ++i) {
        const int e = t + i * 256;
        const float* pp = &partials[(((size_t)(b * NH + h)) * NCHUNK) * 2304 + e];
        float s = 0.f;
        #pragma unroll
        for (int c = 0; c < NCHUNK; ++c) s += pp[(size_t)c * 2304];
        att[e] = s * rq[e / 48] * rk[e % 48] * tp;
    }
    __syncthreads();
    if (t < 48) {
        float m = -1e30f;
        #pragma unroll
        for (int j = 0; j < 48; ++j) m = fmaxf(m, att[t * 48 + j]);
        float s = 0.f;
        for (int j = 0; j < 48; ++j) { float e2 = __expf(att[t * 48 + j] - m); att[t * 48 + j] = e2; s += e2; }
        const float inv = 1.f / s;
        for (int j = 0; j < 48; ++j) att[t * 48 + j] *= inv;
    }
    __syncthreads();
    #pragma unroll
    for (int i = 0; i < 36; ++i) {
        const int idx = t + i * 256;     // 192*48 outputs
        const int oc = idx / 48, d = idx % 48;
        float s = 0.f;
        #pragma unroll
        for (int cc = 0; cc < 48; ++cc)
            s += wproj[oc * 192 + h * 48 + cc] * att[cc * 48 + d];
        Mb[((size_t)b * NC + oc) * NC + h * 48 + d] = f2bf(s);
    }
}

// ---------------- D: out[b] = M[b] @ v[b], fp32 out, px rows ----------------
__global__ __launch_bounds__(256) void k_gemm_out(
    const u16* __restrict__ vp, const u16* __restrict__ Mb,
    float* __restrict__ out)
{
    __shared__ u16 bt[64 * 192];
    const int t = threadIdx.x;
    const int b = blockIdx.y;
    const int p0 = blockIdx.x * 64;

    {
        const int px = t & 63;
        const int cg = t >> 6;              // 0..3
        #pragma unroll
        for (int it = 0; it < 6; ++it) {
            const int c4 = it * 4 + cg;     // 0..23
            const size_t base = ((size_t)b * NC + c4 * 8) * HW + p0 + px;
            v8us pk;
            #pragma unroll
            for (int j = 0; j < 8; ++j) pk[j] = vp[base + (size_t)j * HW];
            *reinterpret_cast<v8us*>(&bt[px * 192 + ((c4 ^ (px & 7)) << 3)]) = pk;
        }
    }
    __syncthreads();

    const int w = t >> 6, l = t & 63, lr = l & 15, lg = l >> 4;
    const int oc0 = w * 48;                 // 4 waves x 48 oc = 192

    v4f acc[4][3];
    #pragma unroll
    for (int mi = 0; mi < 4; ++mi)
        #pragma unroll
        for (int ni = 0; ni < 3; ++ni)
            acc[mi][ni] = (v4f){0.f, 0.f, 0.f, 0.f};

    #pragma unroll
    for (int ks = 0; ks < 6; ++ks) {
        const int k = ks * 32 + lg * 8;
        const int c4 = ks * 4 + lg;
        v8bf a[4];
        #pragma unroll
        for (int mi = 0; mi < 4; ++mi) {
            const int px = mi * 16 + lr;
            a[mi] = *reinterpret_cast<const v8bf*>(&bt[px * 192 + ((c4 ^ (px & 7)) << 3)]);
        }
        #pragma unroll
        for (int ni = 0; ni < 3; ++ni) {
            const int oc = oc0 + ni * 16 + lr;
            const v8bf bw = *reinterpret_cast<const v8bf*>(&Mb[((size_t)b * NC + oc) * NC + k]);
            #pragma unroll
            for (int mi = 0; mi < 4; ++mi)
                acc[mi][ni] = __builtin_amdgcn_mfma_f32_16x16x32_bf16(a[mi], bw, acc[mi][ni], 0, 0, 0);
        }
    }

    #pragma unroll
    for (int mi = 0; mi < 4; ++mi)
        #pragma unroll
        for (int ni = 0; ni < 3; ++ni) {
            const int oc = oc0 + ni * 16 + lr;
            const int px = p0 + mi * 16 + lg * 4;
            *reinterpret_cast<v4f*>(&out[((size_t)b * NC + oc) * HW + px]) = acc[mi][ni];
        }
}

extern "C" void kernel_launch(void* const* d_in, const int* in_sizes, int n_in,
                              void* d_out, int out_size, void* d_ws, size_t ws_size,
                              hipStream_t stream)
{
    (void)in_sizes; (void)n_in; (void)out_size;
    const float* x      = (const float*)d_in[0];
    const float* f      = (const float*)d_in[1];
    const float* w_qkv  = (const float*)d_in[2];
    const float* w_dw   = (const float*)d_in[3];
    const float* w_proj = (const float*)d_in[4];
    const float* temp   = (const float*)d_in[5];

    // ws layout: fixed small stuff + v first, then adaptive qkv staging region
    char* ws = (char*)d_ws;
    u16*   vws      = (u16*)(ws);                      // 8*192*16384*2 = 50,331,648
    u16*   wb       = (u16*)(ws + 50331648);           // 576*192*2     =    221,184
    float* sumsq    = (float*)(ws + 50552832);         // 8*384*4       =     12,288
    float* partials = (float*)(ws + 50565120);         // 8*4*16*2304*4 =  4,718,592
    u16*   Mb       = (u16*)(ws + 55283712);           // 8*192*192*2   =    589,824
    const size_t FIXED = 55873536;
    const size_t PERB  = (size_t)NOC * HW * 2;         // 18,874,368 per batch
    u16*   qkv_raw  = (u16*)(ws + FIXED);

    int g = 1;
    if (ws_size > FIXED + PERB) {
        size_t avail = (ws_size - FIXED) / PERB;
        g = (int)(avail > 8 ? 8 : avail);
        if (g < 1) g = 1;
    }

    u16* qk_scratch = (u16*)d_out;   // q,k planes (bf16) — exactly fills d_out, consumed before final GEMM
    float* out      = (float*)d_out;

    hipLaunchKernelGGL(k_cvt_w, dim3(432), dim3(256), 0, stream, w_qkv, wb, NOC * NC);
    for (int b0 = 0; b0 < NB; b0 += g) {
        const int nb = (b0 + g <= NB) ? g : (NB - b0);
        hipLaunchKernelGGL(k_gemm_qkv, dim3(HW / 64, nb), dim3(256), 0, stream, x, f, wb, qkv_raw, b0);
        hipLaunchKernelGGL(k_dw, dim3(NOC, nb), dim3(256), 0, stream, qkv_raw, w_dw, qk_scratch, vws, sumsq, b0);
    }
    hipLaunchKernelGGL(k_attn, dim3(NCHUNK, NH, NB), dim3(256), 0, stream, qk_scratch, partials);
    hipLaunchKernelGGL(k_smx, dim3(NH, NB), dim3(256), 0, stream, partials, sumsq, w_proj, temp, Mb);
    hipLaunchKernelGGL(k_gemm_out, dim3(HW / 64, NB), dim3(256), 0, stream, vws, Mb, out);
}

// Round 7
// 301.748 us; speedup vs baseline: 1.9627x; 1.0272x over previous
//
#include <hip/hip_runtime.h>
#include <stdint.h>

#define NB 8
#define NC 192
#define NOC 576
#define NH 4
#define HW 16384
#define NCHUNK 16

typedef unsigned short u16;
typedef __bf16 v8bf __attribute__((ext_vector_type(8)));
typedef float v4f __attribute__((ext_vector_type(4)));
typedef u16 v8us __attribute__((ext_vector_type(8)));
typedef u16 v4us __attribute__((ext_vector_type(4)));

__device__ __forceinline__ u16 f2bf(float f) {
    uint32_t u = __float_as_uint(f);
    u += 0x7FFFu + ((u >> 16) & 1u);
    return (u16)(u >> 16);
}
__device__ __forceinline__ float bf2f(u16 u) {
    return __uint_as_float(((uint32_t)u) << 16);
}

// ---------------- P: convert w_qkv to bf16 ----------------
__global__ void k_cvt_w(const float* __restrict__ w, u16* __restrict__ wb, int n) {
    int i = blockIdx.x * 256 + threadIdx.x;
    if (i < n) wb[i] = f2bf(w[i]);
}

// ---------------- A: qkv_raw[bl][oc][p] = W[oc][c] @ (x+f)[b0+bl][c][p] ----------------
// 512 threads / 8 waves over 64px x 576oc tile: wave (wp,wo) = px-half x oc-quarter.
// bt: x+f tile, wt: W K-chunk (reg double-buffered). Epilogue via LDS for full-64B stores.
__global__ __launch_bounds__(512, 4) void k_gemm_qkv(
    const float* __restrict__ x, const float* __restrict__ f,
    const u16* __restrict__ wb, u16* __restrict__ qkv, int b0)
{
    __shared__ u16 bt[64 * 192];    // 24576 B  [px][16B ch-chunks, XOR swizzled]
    __shared__ u16 wt[576 * 32];    // 36864 B  [oc][16B k-chunks, XOR swizzled] / epilogue tile
    const int t = threadIdx.x;
    const int bl = blockIdx.y;
    const int bg = b0 + bl;
    const int p0 = blockIdx.x * 64;

    // stage x+f: 64 px x 192 ch. 512 threads: 3 rounds x 8ch x 2 arrays.
    {
        const int px = t & 63;
        const int cg = t >> 6;              // 0..7
        #pragma unroll
        for (int it = 0; it < 3; ++it) {
            const int c4 = it * 8 + cg;     // 0..23
            const size_t base = ((size_t)bg * NC + c4 * 8) * HW + p0 + px;
            v8us pk;
            #pragma unroll
            for (int j = 0; j < 8; ++j) {
                float v = x[base + (size_t)j * HW] + f[base + (size_t)j * HW];
                pk[j] = f2bf(v);
            }
            *reinterpret_cast<v8us*>(&bt[px * 192 + ((c4 ^ (px & 7)) << 3)]) = pk;
        }
    }

    const int w = t >> 6, l = t & 63, lr = l & 15, lg = l >> 4;
    const int wp = w >> 2;                   // px half (0,1)
    const int wo = w & 3;                    // oc quarter
    const int oc0 = wo * 144;

    v4f acc[2][9];
    #pragma unroll
    for (int mi = 0; mi < 2; ++mi)
        #pragma unroll
        for (int ni = 0; ni < 9; ++ni)
            acc[mi][ni] = (v4f){0.f, 0.f, 0.f, 0.f};

    // W chunk staging: 2304 x 16B per chunk; 512 threads -> 4 full rounds + half round.
    // swizzle: 16B chunk q -> q ^ g(oc), g(oc) = (oc ^ (oc>>2)) & 3 (2-way on write & read)
    v8us wload[5];
    #pragma unroll
    for (int it = 0; it < 5; ++it) {
        const int idx = it * 512 + t;
        if (idx < 2304) {
            const int oc = idx >> 2, q = idx & 3;
            wload[it] = *reinterpret_cast<const v8us*>(&wb[oc * 192 + q * 8]);
        }
    }

    #pragma unroll 1
    for (int ks = 0; ks < 6; ++ks) {
        __syncthreads();   // prev chunk consumed (also orders bt staging on ks=0)
        #pragma unroll
        for (int it = 0; it < 5; ++it) {
            const int idx = it * 512 + t;
            if (idx < 2304) {
                const int oc = idx >> 2, q = idx & 3;
                const int g = (oc ^ (oc >> 2)) & 3;
                *reinterpret_cast<v8us*>(&wt[oc * 32 + ((q ^ g) << 3)]) = wload[it];
            }
        }
        if (ks < 5) {
            #pragma unroll
            for (int it = 0; it < 5; ++it) {
                const int idx = it * 512 + t;
                if (idx < 2304) {
                    const int oc = idx >> 2, q = idx & 3;
                    wload[it] = *reinterpret_cast<const v8us*>(&wb[oc * 192 + (ks + 1) * 32 + q * 8]);
                }
            }
        }
        __syncthreads();

        v8bf a[2];
        #pragma unroll
        for (int mi = 0; mi < 2; ++mi) {
            const int px = wp * 32 + mi * 16 + lr;
            a[mi] = *reinterpret_cast<const v8bf*>(&bt[px * 192 + (((ks * 4 + lg) ^ (px & 7)) << 3)]);
        }
        #pragma unroll
        for (int ni = 0; ni < 9; ++ni) {
            const int oc = oc0 + ni * 16 + lr;
            const int g = (oc ^ (oc >> 2)) & 3;
            const v8bf bw = *reinterpret_cast<const v8bf*>(&wt[oc * 32 + ((lg ^ g) << 3)]);
            #pragma unroll
            for (int mi = 0; mi < 2; ++mi)
                acc[mi][ni] = __builtin_amdgcn_mfma_f32_16x16x32_bf16(a[mi], bw, acc[mi][ni], 0, 0, 0);
        }
    }

    // ---- epilogue: two passes of [576 oc][32 px] through wt; full 64B-run global stores ----
    // LDS layout: wt[oc*32 + ((chunk ^ (oc&7)) * 4)], chunk = 4px (8B) unit 0..7
    #pragma unroll
    for (int pass = 0; pass < 2; ++pass) {
        __syncthreads();   // wt (or prev pass tile) fully consumed
        if (wp == pass) {
            #pragma unroll
            for (int mi = 0; mi < 2; ++mi) {
                #pragma unroll
                for (int ni = 0; ni < 9; ++ni) {
                    const int oc = oc0 + ni * 16 + lr;
                    const int chunk = mi * 4 + lg;           // 0..7 within 32 px
                    const int sch = chunk ^ (oc & 7);
                    v4us pk;
                    pk[0] = f2bf(acc[mi][ni][0]); pk[1] = f2bf(acc[mi][ni][1]);
                    pk[2] = f2bf(acc[mi][ni][2]); pk[3] = f2bf(acc[mi][ni][3]);
                    *reinterpret_cast<v4us*>(&wt[oc * 32 + sch * 4]) = pk;
                }
            }
        }
        __syncthreads();
        // 576 oc x 32 px = 4608 8B-units; 512 threads x 9 rounds; 8 lanes cover one 64B oc-row
        #pragma unroll
        for (int rd = 0; rd < 9; ++rd) {
            const int idx = rd * 512 + t;
            const int oc = idx >> 3;
            const int c = idx & 7;
            v4us v = *reinterpret_cast<v4us*>(&wt[oc * 32 + (c ^ (oc & 7)) * 4]);
            *reinterpret_cast<v4us*>(&qkv[((size_t)bl * NOC + oc) * HW + p0 + pass * 32 + c * 4]) = v;
        }
    }
}

// ---------------- B: depthwise 3x3 + sum-of-squares ----------------
// one (bl,ch) 128x128 plane per block; q,k planes -> d_out scratch (bf16), v -> ws
__global__ __launch_bounds__(256) void k_dw(
    const u16* __restrict__ qkv, const float* __restrict__ wdw,
    u16* __restrict__ qk_out, u16* __restrict__ v_out,
    float* __restrict__ sumsq, int b0)
{
    __shared__ u16 plane[128 * 136];
    __shared__ float red[4];
    const int t = threadIdx.x;
    const int ch = blockIdx.x;
    const int bl = blockIdx.y;
    const int bg = b0 + bl;
    const size_t pbase = ((size_t)bl * NOC + ch) * HW;

    float wk[9];
    #pragma unroll
    for (int i = 0; i < 9; ++i) wk[i] = wdw[ch * 9 + i];

    const int r = t >> 1;
    const int cb = (t & 1) * 64;

    #pragma unroll
    for (int i = 0; i < 8; ++i) {
        v8us v = *reinterpret_cast<const v8us*>(&qkv[pbase + r * 128 + cb + i * 8]);
        *reinterpret_cast<v8us*>(&plane[r * 136 + cb + i * 8]) = v;
    }
    __syncthreads();

    const bool vm = (r > 0), vp = (r < 127);
    const u16* rowm = &plane[(r - 1) * 136];
    const u16* rowc = &plane[r * 136];
    const u16* rowp = &plane[(r + 1) * 136];

    float am, ac, bm, bc, cm, cc2;
    if (cb == 0) { am = 0.f; bm = 0.f; cm = 0.f; }
    else {
        am = vm ? bf2f(rowm[cb - 1]) : 0.f;
        bm = bf2f(rowc[cb - 1]);
        cm = vp ? bf2f(rowp[cb - 1]) : 0.f;
    }
    ac = vm ? bf2f(rowm[cb]) : 0.f;
    bc = bf2f(rowc[cb]);
    cc2 = vp ? bf2f(rowp[cb]) : 0.f;

    uint32_t ov[32];
    float ssq = 0.f;
    #pragma unroll
    for (int xp = 0; xp < 32; ++xp) {
        #pragma unroll
        for (int s2 = 0; s2 < 2; ++s2) {
            const int col = cb + xp * 2 + s2;
            float ap, bp, cp;
            if (col < 127) {
                ap = vm ? bf2f(rowm[col + 1]) : 0.f;
                bp = bf2f(rowc[col + 1]);
                cp = vp ? bf2f(rowp[col + 1]) : 0.f;
            } else { ap = 0.f; bp = 0.f; cp = 0.f; }
            float o = wk[0]*am + wk[1]*ac + wk[2]*ap
                    + wk[3]*bm + wk[4]*bc + wk[5]*bp
                    + wk[6]*cm + wk[7]*cc2 + wk[8]*cp;
            u16 ob = f2bf(o);
            float orr = bf2f(ob);          // consistent with what Gram/GEMM consume
            ssq += orr * orr;
            ov[xp] = (s2 == 0) ? (uint32_t)ob : (ov[xp] | ((uint32_t)ob << 16));
            am = ac; ac = ap; bm = bc; bc = bp; cm = cc2; cc2 = cp;
        }
    }

    __syncthreads();   // all neighbor reads done
    #pragma unroll
    for (int i = 0; i < 32; ++i)
        *reinterpret_cast<uint32_t*>(&plane[r * 136 + cb + i * 2]) = ov[i];
    __syncthreads();

    u16* dst = (ch < 2 * NC) ? (qk_out + ((size_t)bg * (2 * NC) + ch) * HW)
                             : (v_out + ((size_t)bg * NC + (ch - 2 * NC)) * HW);
    // 256 threads x 8 elem x 8 iters = 16384 elements
    #pragma unroll
    for (int i = 0; i < 8; ++i) {
        const int idx = i * 2048 + t * 8;
        const int rr = idx >> 7, cc = idx & 127;
        v8us v = *reinterpret_cast<const v8us*>(&plane[rr * 136 + cc]);
        *reinterpret_cast<v8us*>(&dst[idx]) = v;
    }

    #pragma unroll
    for (int off = 32; off > 0; off >>= 1) ssq += __shfl_down(ssq, off);
    if ((t & 63) == 0) red[t >> 6] = ssq;
    __syncthreads();
    if (t == 0 && ch < 2 * NC) sumsq[bg * (2 * NC) + ch] = red[0] + red[1] + red[2] + red[3];
}

// ---------------- C: partial Gram matrices q@k^T over pixel chunks ----------------
__global__ __launch_bounds__(256) void k_attn(
    const u16* __restrict__ qk, float* __restrict__ partials)
{
    __shared__ float wsum[4 * 2304];
    const int t = threadIdx.x;
    const int chunk = blockIdx.x;   // 0..15
    const int h = blockIdx.y;
    const int b = blockIdx.z;
    const int w = t >> 6, l = t & 63, lr = l & 15, lg = l >> 4;

    const size_t qbase = ((size_t)b * 384 + h * 48) * HW;
    const size_t kbase = ((size_t)b * 384 + 192 + h * 48) * HW;
    const int pb = chunk * 1024 + w * 256;

    v4f acc[3][3];
    #pragma unroll
    for (int mi = 0; mi < 3; ++mi)
        #pragma unroll
        for (int ni = 0; ni < 3; ++ni)
            acc[mi][ni] = (v4f){0.f, 0.f, 0.f, 0.f};

    #pragma unroll
    for (int ks = 0; ks < 8; ++ks) {
        const int k = pb + ks * 32 + lg * 8;
        v8bf a[3], bb[3];
        #pragma unroll
        for (int mi = 0; mi < 3; ++mi)
            a[mi] = *reinterpret_cast<const v8bf*>(&qk[qbase + (size_t)(mi * 16 + lr) * HW + k]);
        #pragma unroll
        for (int ni = 0; ni < 3; ++ni)
            bb[ni] = *reinterpret_cast<const v8bf*>(&qk[kbase + (size_t)(ni * 16 + lr) * HW + k]);
        #pragma unroll
        for (int mi = 0; mi < 3; ++mi)
            #pragma unroll
            for (int ni = 0; ni < 3; ++ni)
                acc[mi][ni] = __builtin_amdgcn_mfma_f32_16x16x32_bf16(a[mi], bb[ni], acc[mi][ni], 0, 0, 0);
    }

    #pragma unroll
    for (int mi = 0; mi < 3; ++mi)
        #pragma unroll
        for (int ni = 0; ni < 3; ++ni)
            #pragma unroll
            for (int r = 0; r < 4; ++r)
                wsum[w * 2304 + (mi * 16 + lg * 4 + r) * 48 + ni * 16 + lr] = acc[mi][ni][r];
    __syncthreads();

    #pragma unroll
    for (int i = 0; i < 9; ++i) {
        const int e = t + i * 256;
        float s = wsum[e] + wsum[2304 + e] + wsum[4608 + e] + wsum[6912 + e];
        partials[(((size_t)(b * NH + h)) * NCHUNK + chunk) * 2304 + e] = s;
    }
}

// ---------------- C2: normalize + softmax + M = Wproj @ blockdiag(attn) ----------------
// one block per (h, b): 32 blocks
__global__ __launch_bounds__(256) void k_smx(
    const float* __restrict__ partials, const float* __restrict__ sumsq,
    const float* __restrict__ wproj, const float* __restrict__ temp,
    u16* __restrict__ Mb)
{
    __shared__ float att[2304];
    __shared__ float rq[48], rk[48];
    const int t = threadIdx.x;
    const int h = blockIdx.x;
    const int b = blockIdx.y;

    if (t < 48) {
        float s = sumsq[b * 384 + h * 48 + t];
        rq[t] = 1.f / fmaxf(sqrtf(s), 1e-12f);
    } else if (t < 96) {
        float s = sumsq[b * 384 + 192 + h * 48 + (t - 48)];
        rk[t - 48] = 1.f / fmaxf(sqrtf(s), 1e-12f);
    }
    __syncthreads();
    const float tp = temp[h];
    #pragma unroll
    for (int i = 0; i < 9; ++i) {
        const int e = t + i * 256;
        const float* pp = &partials[(((size_t)(b * NH + h)) * NCHUNK) * 2304 + e];
        float s = 0.f;
        #pragma unroll
        for (int c = 0; c < NCHUNK; ++c) s += pp[(size_t)c * 2304];
        att[e] = s * rq[e / 48] * rk[e % 48] * tp;
    }
    __syncthreads();
    if (t < 48) {
        float m = -1e30f;
        #pragma unroll
        for (int j = 0; j < 48; ++j) m = fmaxf(m, att[t * 48 + j]);
        float s = 0.f;
        for (int j = 0; j < 48; ++j) { float e2 = __expf(att[t * 48 + j] - m); att[t * 48 + j] = e2; s += e2; }
        const float inv = 1.f / s;
        for (int j = 0; j < 48; ++j) att[t * 48 + j] *= inv;
    }
    __syncthreads();
    #pragma unroll
    for (int i = 0; i < 36; ++i) {
        const int idx = t + i * 256;     // 192*48 outputs
        const int oc = idx / 48, d = idx % 48;
        float s = 0.f;
        #pragma unroll
        for (int cc = 0; cc < 48; ++cc)
            s += wproj[oc * 192 + h * 48 + cc] * att[cc * 48 + d];
        Mb[((size_t)b * NC + oc) * NC + h * 48 + d] = f2bf(s);
    }
}

// ---------------- D: out[b] = M[b] @ v[b], fp32 out, px rows ----------------
__global__ __launch_bounds__(256) void k_gemm_out(
    const u16* __restrict__ vp, const u16* __restrict__ Mb,
    float* __restrict__ out)
{
    __shared__ u16 bt[64 * 192];
    const int t = threadIdx.x;
    const int b = blockIdx.y;
    const int p0 = blockIdx.x * 64;

    {
        const int px = t & 63;
        const int cg = t >> 6;              // 0..3
        #pragma unroll
        for (int it = 0; it < 6; ++it) {
            const int c4 = it * 4 + cg;     // 0..23
            const size_t base = ((size_t)b * NC + c4 * 8) * HW + p0 + px;
            v8us pk;
            #pragma unroll
            for (int j = 0; j < 8; ++j) pk[j] = vp[base + (size_t)j * HW];
            *reinterpret_cast<v8us*>(&bt[px * 192 + ((c4 ^ (px & 7)) << 3)]) = pk;
        }
    }
    __syncthreads();

    const int w = t >> 6, l = t & 63, lr = l & 15, lg = l >> 4;
    const int oc0 = w * 48;                 // 4 waves x 48 oc = 192

    v4f acc[4][3];
    #pragma unroll
    for (int mi = 0; mi < 4; ++mi)
        #pragma unroll
        for (int ni = 0; ni < 3; ++ni)
            acc[mi][ni] = (v4f){0.f, 0.f, 0.f, 0.f};

    #pragma unroll
    for (int ks = 0; ks < 6; ++ks) {
        const int k = ks * 32 + lg * 8;
        const int c4 = ks * 4 + lg;
        v8bf a[4];
        #pragma unroll
        for (int mi = 0; mi < 4; ++mi) {
            const int px = mi * 16 + lr;
            a[mi] = *reinterpret_cast<const v8bf*>(&bt[px * 192 + ((c4 ^ (px & 7)) << 3)]);
        }
        #pragma unroll
        for (int ni = 0; ni < 3; ++ni) {
            const int oc = oc0 + ni * 16 + lr;
            const v8bf bw = *reinterpret_cast<const v8bf*>(&Mb[((size_t)b * NC + oc) * NC + k]);
            #pragma unroll
            for (int mi = 0; mi < 4; ++mi)
                acc[mi][ni] = __builtin_amdgcn_mfma_f32_16x16x32_bf16(a[mi], bw, acc[mi][ni], 0, 0, 0);
        }
    }

    #pragma unroll
    for (int mi = 0; mi < 4; ++mi)
        #pragma unroll
        for (int ni = 0; ni < 3; ++ni) {
            const int oc = oc0 + ni * 16 + lr;
            const int px = p0 + mi * 16 + lg * 4;
            *reinterpret_cast<v4f*>(&out[((size_t)b * NC + oc) * HW + px]) = acc[mi][ni];
        }
}

extern "C" void kernel_launch(void* const* d_in, const int* in_sizes, int n_in,
                              void* d_out, int out_size, void* d_ws, size_t ws_size,
                              hipStream_t stream)
{
    (void)in_sizes; (void)n_in; (void)out_size;
    const float* x      = (const float*)d_in[0];
    const float* f      = (const float*)d_in[1];
    const float* w_qkv  = (const float*)d_in[2];
    const float* w_dw   = (const float*)d_in[3];
    const float* w_proj = (const float*)d_in[4];
    const float* temp   = (const float*)d_in[5];

    // ws layout: fixed small stuff + v first, then adaptive qkv staging region
    char* ws = (char*)d_ws;
    u16*   vws      = (u16*)(ws);                      // 8*192*16384*2 = 50,331,648
    u16*   wb       = (u16*)(ws + 50331648);           // 576*192*2     =    221,184
    float* sumsq    = (float*)(ws + 50552832);         // 8*384*4       =     12,288
    float* partials = (float*)(ws + 50565120);         // 8*4*16*2304*4 =  4,718,592
    u16*   Mb       = (u16*)(ws + 55283712);           // 8*192*192*2   =    589,824
    const size_t FIXED = 55873536;
    const size_t PERB  = (size_t)NOC * HW * 2;         // 18,874,368 per batch
    u16*   qkv_raw  = (u16*)(ws + FIXED);

    int g = 1;
    if (ws_size > FIXED + PERB) {
        size_t avail = (ws_size - FIXED) / PERB;
        g = (int)(avail > 8 ? 8 : avail);
        if (g < 1) g = 1;
    }

    u16* qk_scratch = (u16*)d_out;   // q,k planes (bf16) — exactly fills d_out, consumed before final GEMM
    float* out      = (float*)d_out;

    hipLaunchKernelGGL(k_cvt_w, dim3(432), dim3(256), 0, stream, w_qkv, wb, NOC * NC);
    for (int b0 = 0; b0 < NB; b0 += g) {
        const int nb = (b0 + g <= NB) ? g : (NB - b0);
        hipLaunchKernelGGL(k_gemm_qkv, dim3(HW / 64, nb), dim3(512), 0, stream, x, f, wb, qkv_raw, b0);
        hipLaunchKernelGGL(k_dw, dim3(NOC, nb), dim3(256), 0, stream, qkv_raw, w_dw, qk_scratch, vws, sumsq, b0);
    }
    hipLaunchKernelGGL(k_attn, dim3(NCHUNK, NH, NB), dim3(256), 0, stream, qk_scratch, partials);
    hipLaunchKernelGGL(k_smx, dim3(NH, NB), dim3(256), 0, stream, partials, sumsq, w_proj, temp, Mb);
    hipLaunchKernelGGL(k_gemm_out, dim3(HW / 64, NB), dim3(256), 0, stream, vws, Mb, out);
}

// Round 8
// 295.188 us; speedup vs baseline: 2.0063x; 1.0222x over previous
//
#include <hip/hip_runtime.h>
#include <stdint.h>

#define NB 8
#define NC 192
#define NOC 576
#define NH 4
#define HW 16384
#define NCHUNK 16

typedef unsigned short u16;
typedef __bf16 v8bf __attribute__((ext_vector_type(8)));
typedef float v4f __attribute__((ext_vector_type(4)));
typedef u16 v8us __attribute__((ext_vector_type(8)));
typedef u16 v4us __attribute__((ext_vector_type(4)));

__device__ __forceinline__ u16 f2bf(float f) {
    uint32_t u = __float_as_uint(f);
    u += 0x7FFFu + ((u >> 16) & 1u);
    return (u16)(u >> 16);
}
__device__ __forceinline__ float bf2f(u16 u) {
    return __uint_as_float(((uint32_t)u) << 16);
}

// ---------------- P: convert w_qkv to bf16 ----------------
__global__ void k_cvt_w(const float* __restrict__ w, u16* __restrict__ wb, int n) {
    int i = blockIdx.x * 256 + threadIdx.x;
    if (i < n) wb[i] = f2bf(w[i]);
}

// ---------------- A: qkv_raw tiled [bl][pblk][oc][px64] = W @ (x+f) ----------------
// 512 threads / 8 waves over 64px x 576oc tile. Epilogue stages full C-tile in LDS
// (union with bt/wt) and streams 73.7 KB contiguous per block -> full DRAM efficiency.
__global__ __launch_bounds__(512, 4) void k_gemm_qkv(
    const float* __restrict__ x, const float* __restrict__ f,
    const u16* __restrict__ wb, u16* __restrict__ qkv, int b0)
{
    __shared__ u16 smem[36864];     // 73728 B: loop phase = bt(12288) + wt(18432+...); epilogue = et(36864)
    u16* bt = smem;                 // 64*192 u16  [px][16B ch-chunks, XOR swizzled]
    u16* wt = smem + 12288;         // 576*32 u16  [oc][16B k-chunks, XOR swizzled]
    const int t = threadIdx.x;
    const int bl = blockIdx.y;
    const int bg = b0 + bl;
    const int pblk = blockIdx.x;
    const int p0 = pblk * 64;

    // stage x+f: 64 px x 192 ch. 512 threads: 3 rounds x 8ch x 2 arrays.
    {
        const int px = t & 63;
        const int cg = t >> 6;              // 0..7
        #pragma unroll
        for (int it = 0; it < 3; ++it) {
            const int c4 = it * 8 + cg;     // 0..23
            const size_t base = ((size_t)bg * NC + c4 * 8) * HW + p0 + px;
            v8us pk;
            #pragma unroll
            for (int j = 0; j < 8; ++j) {
                float v = x[base + (size_t)j * HW] + f[base + (size_t)j * HW];
                pk[j] = f2bf(v);
            }
            *reinterpret_cast<v8us*>(&bt[px * 192 + ((c4 ^ (px & 7)) << 3)]) = pk;
        }
    }

    const int w = t >> 6, l = t & 63, lr = l & 15, lg = l >> 4;
    const int wp = w >> 2;                   // px half (0,1)
    const int wo = w & 3;                    // oc quarter
    const int oc0 = wo * 144;

    v4f acc[2][9];
    #pragma unroll
    for (int mi = 0; mi < 2; ++mi)
        #pragma unroll
        for (int ni = 0; ni < 9; ++ni)
            acc[mi][ni] = (v4f){0.f, 0.f, 0.f, 0.f};

    // W chunk staging: 2304 x 16B per chunk; swizzle g(oc) = (oc ^ (oc>>2)) & 3
    v8us wload[5];
    #pragma unroll
    for (int it = 0; it < 5; ++it) {
        const int idx = it * 512 + t;
        if (idx < 2304) {
            const int oc = idx >> 2, q = idx & 3;
            wload[it] = *reinterpret_cast<const v8us*>(&wb[oc * 192 + q * 8]);
        }
    }

    #pragma unroll 1
    for (int ks = 0; ks < 6; ++ks) {
        __syncthreads();   // prev chunk consumed (also orders bt staging on ks=0)
        #pragma unroll
        for (int it = 0; it < 5; ++it) {
            const int idx = it * 512 + t;
            if (idx < 2304) {
                const int oc = idx >> 2, q = idx & 3;
                const int g = (oc ^ (oc >> 2)) & 3;
                *reinterpret_cast<v8us*>(&wt[oc * 32 + ((q ^ g) << 3)]) = wload[it];
            }
        }
        if (ks < 5) {
            #pragma unroll
            for (int it = 0; it < 5; ++it) {
                const int idx = it * 512 + t;
                if (idx < 2304) {
                    const int oc = idx >> 2, q = idx & 3;
                    wload[it] = *reinterpret_cast<const v8us*>(&wb[oc * 192 + (ks + 1) * 32 + q * 8]);
                }
            }
        }
        __syncthreads();

        v8bf a[2];
        #pragma unroll
        for (int mi = 0; mi < 2; ++mi) {
            const int px = wp * 32 + mi * 16 + lr;
            a[mi] = *reinterpret_cast<const v8bf*>(&bt[px * 192 + (((ks * 4 + lg) ^ (px & 7)) << 3)]);
        }
        #pragma unroll
        for (int ni = 0; ni < 9; ++ni) {
            const int oc = oc0 + ni * 16 + lr;
            const int g = (oc ^ (oc >> 2)) & 3;
            const v8bf bw = *reinterpret_cast<const v8bf*>(&wt[oc * 32 + ((lg ^ g) << 3)]);
            #pragma unroll
            for (int mi = 0; mi < 2; ++mi)
                acc[mi][ni] = __builtin_amdgcn_mfma_f32_16x16x32_bf16(a[mi], bw, acc[mi][ni], 0, 0, 0);
        }
    }

    // ---- epilogue: stage full [576 oc][64 px] tile in LDS, stream 73.7 KB contiguous ----
    __syncthreads();   // K-loop frag reads done; reuse whole smem as et
    u16* et = smem;    // et[oc*64 + px], 8B px-units XOR-swizzled by (oc&15)
    #pragma unroll
    for (int mi = 0; mi < 2; ++mi)
        #pragma unroll
        for (int ni = 0; ni < 9; ++ni) {
            const int oc = oc0 + ni * 16 + lr;
            const int u = wp * 8 + mi * 4 + lg;          // px>>2, 0..15
            const int su = u ^ (oc & 15);
            v4us pk;
            pk[0] = f2bf(acc[mi][ni][0]); pk[1] = f2bf(acc[mi][ni][1]);
            pk[2] = f2bf(acc[mi][ni][2]); pk[3] = f2bf(acc[mi][ni][3]);
            *reinterpret_cast<v4us*>(&et[oc * 64 + su * 4]) = pk;
        }
    __syncthreads();
    // 576 oc x 64 px = 4608 16B-chunks; 512 threads x 9 rounds, consecutive addresses
    const size_t obase = ((size_t)bl * 256 + pblk) * 36864;   // 576*64 per pblk
    #pragma unroll
    for (int rd = 0; rd < 9; ++rd) {
        const int idx = rd * 512 + t;        // 0..4607
        const int oc = idx >> 3;
        const int ck = idx & 7;              // 8-px chunk
        const int u0 = (ck * 2) ^ (oc & 15);
        const int u1 = (ck * 2 + 1) ^ (oc & 15);
        v4us lo = *reinterpret_cast<v4us*>(&et[oc * 64 + u0 * 4]);
        v4us hi = *reinterpret_cast<v4us*>(&et[oc * 64 + u1 * 4]);
        v8us o8;
        o8[0] = lo[0]; o8[1] = lo[1]; o8[2] = lo[2]; o8[3] = lo[3];
        o8[4] = hi[0]; o8[5] = hi[1]; o8[6] = hi[2]; o8[7] = hi[3];
        *reinterpret_cast<v8us*>(&qkv[obase + (size_t)idx * 8]) = o8;
    }
}

// ---------------- B: depthwise 3x3 + sum-of-squares ----------------
// one (bl,ch) plane per block; reads tiled qkv layout; q,k -> d_out scratch, v -> ws
__global__ __launch_bounds__(256) void k_dw(
    const u16* __restrict__ qkv, const float* __restrict__ wdw,
    u16* __restrict__ qk_out, u16* __restrict__ v_out,
    float* __restrict__ sumsq, int b0)
{
    __shared__ u16 plane[128 * 136];
    __shared__ float red[4];
    const int t = threadIdx.x;
    const int ch = blockIdx.x;
    const int bl = blockIdx.y;
    const int bg = b0 + bl;

    float wk[9];
    #pragma unroll
    for (int i = 0; i < 9; ++i) wk[i] = wdw[ch * 9 + i];

    const int r = t >> 1;
    const int cb = (t & 1) * 64;

    // gather plane from tiled layout: 256 pblks x 128B fully-used segments
    {
        const u16* src = qkv + ((size_t)bl * 256) * 36864 + (size_t)ch * 64;
        #pragma unroll
        for (int i = 0; i < 8; ++i) {
            const int e = i * 2048 + t * 8;
            const int pblk = e >> 6, px = e & 63;
            v8us v = *reinterpret_cast<const v8us*>(&src[(size_t)pblk * 36864 + px]);
            const int rr = e >> 7, cc = e & 127;
            *reinterpret_cast<v8us*>(&plane[rr * 136 + cc]) = v;
        }
    }
    __syncthreads();

    const bool vm = (r > 0), vp = (r < 127);
    const u16* rowm = &plane[(r - 1) * 136];
    const u16* rowc = &plane[r * 136];
    const u16* rowp = &plane[(r + 1) * 136];

    float am, ac, bm, bc, cm, cc2;
    if (cb == 0) { am = 0.f; bm = 0.f; cm = 0.f; }
    else {
        am = vm ? bf2f(rowm[cb - 1]) : 0.f;
        bm = bf2f(rowc[cb - 1]);
        cm = vp ? bf2f(rowp[cb - 1]) : 0.f;
    }
    ac = vm ? bf2f(rowm[cb]) : 0.f;
    bc = bf2f(rowc[cb]);
    cc2 = vp ? bf2f(rowp[cb]) : 0.f;

    uint32_t ov[32];
    float ssq = 0.f;
    #pragma unroll
    for (int xp = 0; xp < 32; ++xp) {
        #pragma unroll
        for (int s2 = 0; s2 < 2; ++s2) {
            const int col = cb + xp * 2 + s2;
            float ap, bp, cp;
            if (col < 127) {
                ap = vm ? bf2f(rowm[col + 1]) : 0.f;
                bp = bf2f(rowc[col + 1]);
                cp = vp ? bf2f(rowp[col + 1]) : 0.f;
            } else { ap = 0.f; bp = 0.f; cp = 0.f; }
            float o = wk[0]*am + wk[1]*ac + wk[2]*ap
                    + wk[3]*bm + wk[4]*bc + wk[5]*bp
                    + wk[6]*cm + wk[7]*cc2 + wk[8]*cp;
            u16 ob = f2bf(o);
            float orr = bf2f(ob);          // consistent with what Gram/GEMM consume
            ssq += orr * orr;
            ov[xp] = (s2 == 0) ? (uint32_t)ob : (ov[xp] | ((uint32_t)ob << 16));
            am = ac; ac = ap; bm = bc; bc = bp; cm = cc2; cc2 = cp;
        }
    }

    __syncthreads();   // all neighbor reads done
    #pragma unroll
    for (int i = 0; i < 32; ++i)
        *reinterpret_cast<uint32_t*>(&plane[r * 136 + cb + i * 2]) = ov[i];
    __syncthreads();

    u16* dst = (ch < 2 * NC) ? (qk_out + ((size_t)bg * (2 * NC) + ch) * HW)
                             : (v_out + ((size_t)bg * NC + (ch - 2 * NC)) * HW);
    // 256 threads x 8 elem x 8 iters = 16384 elements
    #pragma unroll
    for (int i = 0; i < 8; ++i) {
        const int idx = i * 2048 + t * 8;
        const int rr = idx >> 7, cc = idx & 127;
        v8us v = *reinterpret_cast<const v8us*>(&plane[rr * 136 + cc]);
        *reinterpret_cast<v8us*>(&dst[idx]) = v;
    }

    #pragma unroll
    for (int off = 32; off > 0; off >>= 1) ssq += __shfl_down(ssq, off);
    if ((t & 63) == 0) red[t >> 6] = ssq;
    __syncthreads();
    if (t == 0 && ch < 2 * NC) sumsq[bg * (2 * NC) + ch] = red[0] + red[1] + red[2] + red[3];
}

// ---------------- C: partial Gram matrices q@k^T over pixel chunks ----------------
__global__ __launch_bounds__(256) void k_attn(
    const u16* __restrict__ qk, float* __restrict__ partials)
{
    __shared__ float wsum[4 * 2304];
    const int t = threadIdx.x;
    const int chunk = blockIdx.x;   // 0..15
    const int h = blockIdx.y;
    const int b = blockIdx.z;
    const int w = t >> 6, l = t & 63, lr = l & 15, lg = l >> 4;

    const size_t qbase = ((size_t)b * 384 + h * 48) * HW;
    const size_t kbase = ((size_t)b * 384 + 192 + h * 48) * HW;
    const int pb = chunk * 1024 + w * 256;

    v4f acc[3][3];
    #pragma unroll
    for (int mi = 0; mi < 3; ++mi)
        #pragma unroll
        for (int ni = 0; ni < 3; ++ni)
            acc[mi][ni] = (v4f){0.f, 0.f, 0.f, 0.f};

    #pragma unroll
    for (int ks = 0; ks < 8; ++ks) {
        const int k = pb + ks * 32 + lg * 8;
        v8bf a[3], bb[3];
        #pragma unroll
        for (int mi = 0; mi < 3; ++mi)
            a[mi] = *reinterpret_cast<const v8bf*>(&qk[qbase + (size_t)(mi * 16 + lr) * HW + k]);
        #pragma unroll
        for (int ni = 0; ni < 3; ++ni)
            bb[ni] = *reinterpret_cast<const v8bf*>(&qk[kbase + (size_t)(ni * 16 + lr) * HW + k]);
        #pragma unroll
        for (int mi = 0; mi < 3; ++mi)
            #pragma unroll
            for (int ni = 0; ni < 3; ++ni)
                acc[mi][ni] = __builtin_amdgcn_mfma_f32_16x16x32_bf16(a[mi], bb[ni], acc[mi][ni], 0, 0, 0);
    }

    #pragma unroll
    for (int mi = 0; mi < 3; ++mi)
        #pragma unroll
        for (int ni = 0; ni < 3; ++ni)
            #pragma unroll
            for (int r = 0; r < 4; ++r)
                wsum[w * 2304 + (mi * 16 + lg * 4 + r) * 48 + ni * 16 + lr] = acc[mi][ni][r];
    __syncthreads();

    #pragma unroll
    for (int i = 0; i < 9; ++i) {
        const int e = t + i * 256;
        float s = wsum[e] + wsum[2304 + e] + wsum[4608 + e] + wsum[6912 + e];
        partials[(((size_t)(b * NH + h)) * NCHUNK + chunk) * 2304 + e] = s;
    }
}

// ---------------- C2: normalize + softmax + M = Wproj @ blockdiag(attn) ----------------
// one block per (h, b): 32 blocks
__global__ __launch_bounds__(256) void k_smx(
    const float* __restrict__ partials, const float* __restrict__ sumsq,
    const float* __restrict__ wproj, const float* __restrict__ temp,
    u16* __restrict__ Mb)
{
    __shared__ float att[2304];
    __shared__ float rq[48], rk[48];
    const int t = threadIdx.x;
    const int h = blockIdx.x;
    const int b = blockIdx.y;

    if (t < 48) {
        float s = sumsq[b * 384 + h * 48 + t];
        rq[t] = 1.f / fmaxf(sqrtf(s), 1e-12f);
    } else if (t < 96) {
        float s = sumsq[b * 384 + 192 + h * 48 + (t - 48)];
        rk[t - 48] = 1.f / fmaxf(sqrtf(s), 1e-12f);
    }
    __syncthreads();
    const float tp = temp[h];
    #pragma unroll
    for (int i = 0; i < 9; ++i) {
        const int e = t + i * 256;
        const float* pp = &partials[(((size_t)(b * NH + h)) * NCHUNK) * 2304 + e];
        float s = 0.f;
        #pragma unroll
        for (int c = 0; c < NCHUNK; ++c) s += pp[(size_t)c * 2304];
        att[e] = s * rq[e / 48] * rk[e % 48] * tp;
    }
    __syncthreads();
    if (t < 48) {
        float m = -1e30f;
        #pragma unroll
        for (int j = 0; j < 48; ++j) m = fmaxf(m, att[t * 48 + j]);
        float s = 0.f;
        for (int j = 0; j < 48; ++j) { float e2 = __expf(att[t * 48 + j] - m); att[t * 48 + j] = e2; s += e2; }
        const float inv = 1.f / s;
        for (int j = 0; j < 48; ++j) att[t * 48 + j] *= inv;
    }
    __syncthreads();
    #pragma unroll
    for (int i = 0; i < 36; ++i) {
        const int idx = t + i * 256;     // 192*48 outputs
        const int oc = idx / 48, d = idx % 48;
        float s = 0.f;
        #pragma unroll
        for (int cc = 0; cc < 48; ++cc)
            s += wproj[oc * 192 + h * 48 + cc] * att[cc * 48 + d];
        Mb[((size_t)b * NC + oc) * NC + h * 48 + d] = f2bf(s);
    }
}

// ---------------- D: out[b] = M[b] @ v[b], fp32 out, px rows ----------------
__global__ __launch_bounds__(256) void k_gemm_out(
    const u16* __restrict__ vp, const u16* __restrict__ Mb,
    float* __restrict__ out)
{
    __shared__ u16 bt[64 * 192];
    const int t = threadIdx.x;
    const int b = blockIdx.y;
    const int p0 = blockIdx.x * 64;

    {
        const int px = t & 63;
        const int cg = t >> 6;              // 0..3
        #pragma unroll
        for (int it = 0; it < 6; ++it) {
            const int c4 = it * 4 + cg;     // 0..23
            const size_t base = ((size_t)b * NC + c4 * 8) * HW + p0 + px;
            v8us pk;
            #pragma unroll
            for (int j = 0; j < 8; ++j) pk[j] = vp[base + (size_t)j * HW];
            *reinterpret_cast<v8us*>(&bt[px * 192 + ((c4 ^ (px & 7)) << 3)]) = pk;
        }
    }
    __syncthreads();

    const int w = t >> 6, l = t & 63, lr = l & 15, lg = l >> 4;
    const int oc0 = w * 48;                 // 4 waves x 48 oc = 192

    v4f acc[4][3];
    #pragma unroll
    for (int mi = 0; mi < 4; ++mi)
        #pragma unroll
        for (int ni = 0; ni < 3; ++ni)
            acc[mi][ni] = (v4f){0.f, 0.f, 0.f, 0.f};

    #pragma unroll
    for (int ks = 0; ks < 6; ++ks) {
        const int k = ks * 32 + lg * 8;
        const int c4 = ks * 4 + lg;
        v8bf a[4];
        #pragma unroll
        for (int mi = 0; mi < 4; ++mi) {
            const int px = mi * 16 + lr;
            a[mi] = *reinterpret_cast<const v8bf*>(&bt[px * 192 + ((c4 ^ (px & 7)) << 3)]);
        }
        #pragma unroll
        for (int ni = 0; ni < 3; ++ni) {
            const int oc = oc0 + ni * 16 + lr;
            const v8bf bw = *reinterpret_cast<const v8bf*>(&Mb[((size_t)b * NC + oc) * NC + k]);
            #pragma unroll
            for (int mi = 0; mi < 4; ++mi)
                acc[mi][ni] = __builtin_amdgcn_mfma_f32_16x16x32_bf16(a[mi], bw, acc[mi][ni], 0, 0, 0);
        }
    }

    #pragma unroll
    for (int mi = 0; mi < 4; ++mi)
        #pragma unroll
        for (int ni = 0; ni < 3; ++ni) {
            const int oc = oc0 + ni * 16 + lr;
            const int px = p0 + mi * 16 + lg * 4;
            *reinterpret_cast<v4f*>(&out[((size_t)b * NC + oc) * HW + px]) = acc[mi][ni];
        }
}

extern "C" void kernel_launch(void* const* d_in, const int* in_sizes, int n_in,
                              void* d_out, int out_size, void* d_ws, size_t ws_size,
                              hipStream_t stream)
{
    (void)in_sizes; (void)n_in; (void)out_size;
    const float* x      = (const float*)d_in[0];
    const float* f      = (const float*)d_in[1];
    const float* w_qkv  = (const float*)d_in[2];
    const float* w_dw   = (const float*)d_in[3];
    const float* w_proj = (const float*)d_in[4];
    const float* temp   = (const float*)d_in[5];

    // ws layout: fixed small stuff + v first, then adaptive qkv staging region
    char* ws = (char*)d_ws;
    u16*   vws      = (u16*)(ws);                      // 8*192*16384*2 = 50,331,648
    u16*   wb       = (u16*)(ws + 50331648);           // 576*192*2     =    221,184
    float* sumsq    = (float*)(ws + 50552832);         // 8*384*4       =     12,288
    float* partials = (float*)(ws + 50565120);         // 8*4*16*2304*4 =  4,718,592
    u16*   Mb       = (u16*)(ws + 55283712);           // 8*192*192*2   =    589,824
    const size_t FIXED = 55873536;
    const size_t PERB  = (size_t)NOC * HW * 2;         // 18,874,368 per batch
    u16*   qkv_raw  = (u16*)(ws + FIXED);

    int g = 1;
    if (ws_size > FIXED + PERB) {
        size_t avail = (ws_size - FIXED) / PERB;
        g = (int)(avail > 8 ? 8 : avail);
        if (g < 1) g = 1;
    }

    u16* qk_scratch = (u16*)d_out;   // q,k planes (bf16) — exactly fills d_out, consumed before final GEMM
    float* out      = (float*)d_out;

    hipLaunchKernelGGL(k_cvt_w, dim3(432), dim3(256), 0, stream, w_qkv, wb, NOC * NC);
    for (int b0 = 0; b0 < NB; b0 += g) {
        const int nb = (b0 + g <= NB) ? g : (NB - b0);
        hipLaunchKernelGGL(k_gemm_qkv, dim3(HW / 64, nb), dim3(512), 0, stream, x, f, wb, qkv_raw, b0);
        hipLaunchKernelGGL(k_dw, dim3(NOC, nb), dim3(256), 0, stream, qkv_raw, w_dw, qk_scratch, vws, sumsq, b0);
    }
    hipLaunchKernelGGL(k_attn, dim3(NCHUNK, NH, NB), dim3(256), 0, stream, qk_scratch, partials);
    hipLaunchKernelGGL(k_smx, dim3(NH, NB), dim3(256), 0, stream, partials, sumsq, w_proj, temp, Mb);
    hipLaunchKernelGGL(k_gemm_out, dim3(HW / 64, NB), dim3(256), 0, stream, vws, Mb, out);
}

// Round 9
// 285.205 us; speedup vs baseline: 2.0765x; 1.0350x over previous
//
#include <hip/hip_runtime.h>
#include <stdint.h>

#define NB 8
#define NC 192
#define NOC 576
#define NH 4
#define HW 16384
#define NCHUNK 16

typedef unsigned short u16;
typedef __bf16 v8bf __attribute__((ext_vector_type(8)));
typedef float v4f __attribute__((ext_vector_type(4)));
typedef u16 v8us __attribute__((ext_vector_type(8)));
typedef u16 v4us __attribute__((ext_vector_type(4)));

__device__ __forceinline__ u16 f2bf(float f) {
    uint32_t u = __float_as_uint(f);
    u += 0x7FFFu + ((u >> 16) & 1u);
    return (u16)(u >> 16);
}
__device__ __forceinline__ float bf2f(u16 u) {
    return __uint_as_float(((uint32_t)u) << 16);
}

// ---------------- P: convert w_qkv to bf16 ----------------
__global__ void k_cvt_w(const float* __restrict__ w, u16* __restrict__ wb, int n) {
    int i = blockIdx.x * 256 + threadIdx.x;
    if (i < n) wb[i] = f2bf(w[i]);
}

// ---------------- A: qkv tiled [bl][pblk64][oc][px64] = W @ (x+f) ----------------
// 1024 threads / 16 waves over 128px x 576oc tile; wave (wp 0..3 px-quarter, wo 0..3 oc-quarter).
// W chunk reg-double-buffered -> LDS; epilogue: 2 passes of [576][64] staged in LDS,
// streamed as 73.7 KB contiguous runs. Output layout identical to R8 (k_dw unchanged).
__global__ __launch_bounds__(1024) void k_gemm_qkv(
    const float* __restrict__ x, const float* __restrict__ f,
    const u16* __restrict__ wb, u16* __restrict__ qkv, int b0)
{
    __shared__ u16 smem[43008];     // 86016 B: bt(49152) + wt(36864); epilogue reuses as et(73728)
    u16* bt = smem;                 // 128*192 u16 [px][16B ch-chunks, XOR swizzled]
    u16* wt = smem + 24576;         // 576*32 u16  [oc][16B k-chunks, XOR swizzled]
    const int t = threadIdx.x;
    const int bl = blockIdx.y;
    const int bg = b0 + bl;
    const int p0 = blockIdx.x * 128;

    // stage x+f: 128 px x 192 ch. coalesced scalar loads (1024B/instr), packed b128 LDS writes.
    {
        const int px = t & 127;
        const int cg = t >> 7;              // 0..7
        #pragma unroll
        for (int it = 0; it < 3; ++it) {
            const int c4 = it * 8 + cg;     // 0..23
            const size_t base = ((size_t)bg * NC + c4 * 8) * HW + p0 + px;
            v8us pk;
            #pragma unroll
            for (int j = 0; j < 8; ++j) {
                float v = x[base + (size_t)j * HW] + f[base + (size_t)j * HW];
                pk[j] = f2bf(v);
            }
            *reinterpret_cast<v8us*>(&bt[px * 192 + ((c4 ^ (px & 7)) << 3)]) = pk;
        }
    }

    const int w = t >> 6, l = t & 63, lr = l & 15, lg = l >> 4;
    const int wp = w >> 2;                   // px quarter (0..3)
    const int wo = w & 3;                    // oc quarter
    const int oc0 = wo * 144;

    v4f acc[2][9];
    #pragma unroll
    for (int mi = 0; mi < 2; ++mi)
        #pragma unroll
        for (int ni = 0; ni < 9; ++ni)
            acc[mi][ni] = (v4f){0.f, 0.f, 0.f, 0.f};

    // W chunk staging: 2304 x 16B per chunk; 1024 threads -> 3 rounds (last partial).
    v8us wload[3];
    #pragma unroll
    for (int it = 0; it < 3; ++it) {
        const int idx = it * 1024 + t;
        if (idx < 2304) {
            const int oc = idx >> 2, q = idx & 3;
            wload[it] = *reinterpret_cast<const v8us*>(&wb[oc * 192 + q * 8]);
        }
    }

    #pragma unroll 1
    for (int ks = 0; ks < 6; ++ks) {
        __syncthreads();   // prev chunk consumed (also orders bt staging on ks=0)
        #pragma unroll
        for (int it = 0; it < 3; ++it) {
            const int idx = it * 1024 + t;
            if (idx < 2304) {
                const int oc = idx >> 2, q = idx & 3;
                const int g = (oc ^ (oc >> 2)) & 3;
                *reinterpret_cast<v8us*>(&wt[oc * 32 + ((q ^ g) << 3)]) = wload[it];
            }
        }
        if (ks < 5) {
            #pragma unroll
            for (int it = 0; it < 3; ++it) {
                const int idx = it * 1024 + t;
                if (idx < 2304) {
                    const int oc = idx >> 2, q = idx & 3;
                    wload[it] = *reinterpret_cast<const v8us*>(&wb[oc * 192 + (ks + 1) * 32 + q * 8]);
                }
            }
        }
        __syncthreads();

        v8bf a[2];
        #pragma unroll
        for (int mi = 0; mi < 2; ++mi) {
            const int px = wp * 32 + mi * 16 + lr;
            a[mi] = *reinterpret_cast<const v8bf*>(&bt[px * 192 + (((ks * 4 + lg) ^ (px & 7)) << 3)]);
        }
        #pragma unroll
        for (int ni = 0; ni < 9; ++ni) {
            const int oc = oc0 + ni * 16 + lr;
            const int g = (oc ^ (oc >> 2)) & 3;
            const v8bf bw = *reinterpret_cast<const v8bf*>(&wt[oc * 32 + ((lg ^ g) << 3)]);
            #pragma unroll
            for (int mi = 0; mi < 2; ++mi)
                acc[mi][ni] = __builtin_amdgcn_mfma_f32_16x16x32_bf16(a[mi], bw, acc[mi][ni], 0, 0, 0);
        }
    }

    // ---- epilogue: 2 passes of [576 oc][64 px] through LDS; contiguous 73.7 KB streams ----
    u16* et = smem;
    #pragma unroll
    for (int pass = 0; pass < 2; ++pass) {
        __syncthreads();   // frag reads / prev pass reads done
        if ((wp >> 1) == pass) {
            #pragma unroll
            for (int mi = 0; mi < 2; ++mi)
                #pragma unroll
                for (int ni = 0; ni < 9; ++ni) {
                    const int oc = oc0 + ni * 16 + lr;
                    const int u = (wp & 1) * 8 + mi * 4 + lg;    // 8B px-unit 0..15
                    const int su = u ^ (oc & 15);
                    v4us pk;
                    pk[0] = f2bf(acc[mi][ni][0]); pk[1] = f2bf(acc[mi][ni][1]);
                    pk[2] = f2bf(acc[mi][ni][2]); pk[3] = f2bf(acc[mi][ni][3]);
                    *reinterpret_cast<v4us*>(&et[oc * 64 + su * 4]) = pk;
                }
        }
        __syncthreads();
        const size_t obase = ((size_t)bl * 256 + blockIdx.x * 2 + pass) * 36864;
        #pragma unroll
        for (int rd = 0; rd < 5; ++rd) {
            const int idx = rd * 1024 + t;       // 0..4607 16B-chunks
            if (idx < 4608) {
                const int oc = idx >> 3;
                const int ck = idx & 7;
                const int u0 = (ck * 2) ^ (oc & 15);
                const int u1 = (ck * 2 + 1) ^ (oc & 15);
                v4us lo = *reinterpret_cast<v4us*>(&et[oc * 64 + u0 * 4]);
                v4us hi = *reinterpret_cast<v4us*>(&et[oc * 64 + u1 * 4]);
                v8us o8;
                o8[0] = lo[0]; o8[1] = lo[1]; o8[2] = lo[2]; o8[3] = lo[3];
                o8[4] = hi[0]; o8[5] = hi[1]; o8[6] = hi[2]; o8[7] = hi[3];
                *reinterpret_cast<v8us*>(&qkv[obase + (size_t)idx * 8]) = o8;
            }
        }
    }
}

// ---------------- B: depthwise 3x3 + sum-of-squares (512 threads) ----------------
__global__ __launch_bounds__(512) void k_dw(
    const u16* __restrict__ qkv, const float* __restrict__ wdw,
    u16* __restrict__ qk_out, u16* __restrict__ v_out,
    float* __restrict__ sumsq, int b0)
{
    __shared__ u16 plane[128 * 136];
    __shared__ float red[8];
    const int t = threadIdx.x;
    const int ch = blockIdx.x;
    const int bl = blockIdx.y;
    const int bg = b0 + bl;

    float wk[9];
    #pragma unroll
    for (int i = 0; i < 9; ++i) wk[i] = wdw[ch * 9 + i];

    const int r = t >> 2;
    const int cq = (t & 3) * 32;

    // gather plane from tiled layout: 256 pblks x 128B fully-used segments
    {
        const u16* src = qkv + ((size_t)bl * 256) * 36864 + (size_t)ch * 64;
        #pragma unroll
        for (int i = 0; i < 4; ++i) {
            const int e = i * 4096 + t * 8;
            const int pblk = e >> 6, px = e & 63;
            v8us v = *reinterpret_cast<const v8us*>(&src[(size_t)pblk * 36864 + px]);
            const int rr = e >> 7, cc = e & 127;
            *reinterpret_cast<v8us*>(&plane[rr * 136 + cc]) = v;
        }
    }
    __syncthreads();

    const bool vm = (r > 0), vp = (r < 127);
    const u16* rowm = &plane[(r - 1) * 136];
    const u16* rowc = &plane[r * 136];
    const u16* rowp = &plane[(r + 1) * 136];

    float am, ac, bm, bc, cm, cc2;
    if (cq == 0) { am = 0.f; bm = 0.f; cm = 0.f; }
    else {
        am = vm ? bf2f(rowm[cq - 1]) : 0.f;
        bm = bf2f(rowc[cq - 1]);
        cm = vp ? bf2f(rowp[cq - 1]) : 0.f;
    }
    ac = vm ? bf2f(rowm[cq]) : 0.f;
    bc = bf2f(rowc[cq]);
    cc2 = vp ? bf2f(rowp[cq]) : 0.f;

    uint32_t ov[16];
    float ssq = 0.f;
    #pragma unroll
    for (int xp = 0; xp < 16; ++xp) {
        #pragma unroll
        for (int s2 = 0; s2 < 2; ++s2) {
            const int col = cq + xp * 2 + s2;
            float ap, bp, cp;
            if (col < 127) {
                ap = vm ? bf2f(rowm[col + 1]) : 0.f;
                bp = bf2f(rowc[col + 1]);
                cp = vp ? bf2f(rowp[col + 1]) : 0.f;
            } else { ap = 0.f; bp = 0.f; cp = 0.f; }
            float o = wk[0]*am + wk[1]*ac + wk[2]*ap
                    + wk[3]*bm + wk[4]*bc + wk[5]*bp
                    + wk[6]*cm + wk[7]*cc2 + wk[8]*cp;
            u16 ob = f2bf(o);
            float orr = bf2f(ob);          // consistent with what Gram/GEMM consume
            ssq += orr * orr;
            ov[xp] = (s2 == 0) ? (uint32_t)ob : (ov[xp] | ((uint32_t)ob << 16));
            am = ac; ac = ap; bm = bc; bc = bp; cm = cc2; cc2 = cp;
        }
    }

    __syncthreads();   // all neighbor reads done
    #pragma unroll
    for (int k = 0; k < 4; ++k) {
        uint4 w4;
        w4.x = ov[k * 4 + 0]; w4.y = ov[k * 4 + 1];
        w4.z = ov[k * 4 + 2]; w4.w = ov[k * 4 + 3];
        *reinterpret_cast<uint4*>(&plane[r * 136 + cq + k * 8]) = w4;
    }
    __syncthreads();

    u16* dst = (ch < 2 * NC) ? (qk_out + ((size_t)bg * (2 * NC) + ch) * HW)
                             : (v_out + ((size_t)bg * NC + (ch - 2 * NC)) * HW);
    // 512 threads x 8 elem x 4 iters = 16384 elements, contiguous 16B lanes
    #pragma unroll
    for (int i = 0; i < 4; ++i) {
        const int idx = i * 4096 + t * 8;
        const int rr = idx >> 7, cc = idx & 127;
        v8us v = *reinterpret_cast<const v8us*>(&plane[rr * 136 + cc]);
        *reinterpret_cast<v8us*>(&dst[idx]) = v;
    }

    #pragma unroll
    for (int off = 32; off > 0; off >>= 1) ssq += __shfl_down(ssq, off);
    if ((t & 63) == 0) red[t >> 6] = ssq;
    __syncthreads();
    if (t == 0 && ch < 2 * NC) {
        float s = 0.f;
        #pragma unroll
        for (int i = 0; i < 8; ++i) s += red[i];
        sumsq[bg * (2 * NC) + ch] = s;
    }
}

// ---------------- C: partial Gram matrices q@k^T over pixel chunks ----------------
__global__ __launch_bounds__(256) void k_attn(
    const u16* __restrict__ qk, float* __restrict__ partials)
{
    __shared__ float wsum[4 * 2304];
    const int t = threadIdx.x;
    const int chunk = blockIdx.x;   // 0..15
    const int h = blockIdx.y;
    const int b = blockIdx.z;
    const int w = t >> 6, l = t & 63, lr = l & 15, lg = l >> 4;

    const size_t qbase = ((size_t)b * 384 + h * 48) * HW;
    const size_t kbase = ((size_t)b * 384 + 192 + h * 48) * HW;
    const int pb = chunk * 1024 + w * 256;

    v4f acc[3][3];
    #pragma unroll
    for (int mi = 0; mi < 3; ++mi)
        #pragma unroll
        for (int ni = 0; ni < 3; ++ni)
            acc[mi][ni] = (v4f){0.f, 0.f, 0.f, 0.f};

    #pragma unroll
    for (int ks = 0; ks < 8; ++ks) {
        const int k = pb + ks * 32 + lg * 8;
        v8bf a[3], bb[3];
        #pragma unroll
        for (int mi = 0; mi < 3; ++mi)
            a[mi] = *reinterpret_cast<const v8bf*>(&qk[qbase + (size_t)(mi * 16 + lr) * HW + k]);
        #pragma unroll
        for (int ni = 0; ni < 3; ++ni)
            bb[ni] = *reinterpret_cast<const v8bf*>(&qk[kbase + (size_t)(ni * 16 + lr) * HW + k]);
        #pragma unroll
        for (int mi = 0; mi < 3; ++mi)
            #pragma unroll
            for (int ni = 0; ni < 3; ++ni)
                acc[mi][ni] = __builtin_amdgcn_mfma_f32_16x16x32_bf16(a[mi], bb[ni], acc[mi][ni], 0, 0, 0);
    }

    #pragma unroll
    for (int mi = 0; mi < 3; ++mi)
        #pragma unroll
        for (int ni = 0; ni < 3; ++ni)
            #pragma unroll
            for (int r = 0; r < 4; ++r)
                wsum[w * 2304 + (mi * 16 + lg * 4 + r) * 48 + ni * 16 + lr] = acc[mi][ni][r];
    __syncthreads();

    #pragma unroll
    for (int i = 0; i < 9; ++i) {
        const int e = t + i * 256;
        float s = wsum[e] + wsum[2304 + e] + wsum[4608 + e] + wsum[6912 + e];
        partials[(((size_t)(b * NH + h)) * NCHUNK + chunk) * 2304 + e] = s;
    }
}

// ---------------- C2: normalize + softmax + M = Wproj @ blockdiag(attn) ----------------
// one block per (h, b): 32 blocks
__global__ __launch_bounds__(256) void k_smx(
    const float* __restrict__ partials, const float* __restrict__ sumsq,
    const float* __restrict__ wproj, const float* __restrict__ temp,
    u16* __restrict__ Mb)
{
    __shared__ float att[2304];
    __shared__ float rq[48], rk[48];
    const int t = threadIdx.x;
    const int h = blockIdx.x;
    const int b = blockIdx.y;

    if (t < 48) {
        float s = sumsq[b * 384 + h * 48 + t];
        rq[t] = 1.f / fmaxf(sqrtf(s), 1e-12f);
    } else if (t < 96) {
        float s = sumsq[b * 384 + 192 + h * 48 + (t - 48)];
        rk[t - 48] = 1.f / fmaxf(sqrtf(s), 1e-12f);
    }
    __syncthreads();
    const float tp = temp[h];
    #pragma unroll
    for (int i = 0; i < 9; ++i) {
        const int e = t + i * 256;
        const float* pp = &partials[(((size_t)(b * NH + h)) * NCHUNK) * 2304 + e];
        float s = 0.f;
        #pragma unroll
        for (int c = 0; c < NCHUNK; ++c) s += pp[(size_t)c * 2304];
        att[e] = s * rq[e / 48] * rk[e % 48] * tp;
    }
    __syncthreads();
    if (t < 48) {
        float m = -1e30f;
        #pragma unroll
        for (int j = 0; j < 48; ++j) m = fmaxf(m, att[t * 48 + j]);
        float s = 0.f;
        for (int j = 0; j < 48; ++j) { float e2 = __expf(att[t * 48 + j] - m); att[t * 48 + j] = e2; s += e2; }
        const float inv = 1.f / s;
        for (int j = 0; j < 48; ++j) att[t * 48 + j] *= inv;
    }
    __syncthreads();
    #pragma unroll
    for (int i = 0; i < 36; ++i) {
        const int idx = t + i * 256;     // 192*48 outputs
        const int oc = idx / 48, d = idx % 48;
        float s = 0.f;
        #pragma unroll
        for (int cc = 0; cc < 48; ++cc)
            s += wproj[oc * 192 + h * 48 + cc] * att[cc * 48 + d];
        Mb[((size_t)b * NC + oc) * NC + h * 48 + d] = f2bf(s);
    }
}

// ---------------- D: out[b] = M[b] @ v[b], fp32 out; LDS epilogue for full-line stores ----------------
__global__ __launch_bounds__(256) void k_gemm_out(
    const u16* __restrict__ vp, const u16* __restrict__ Mb,
    float* __restrict__ out)
{
    __shared__ float smemf[12288];   // 49152 B: staging bt (first 24576 B) / epilogue et
    u16* bt = reinterpret_cast<u16*>(smemf);
    const int t = threadIdx.x;
    const int b = blockIdx.y;
    const int p0 = blockIdx.x * 64;

    {
        const int px = t & 63;
        const int cg = t >> 6;              // 0..3
        #pragma unroll
        for (int it = 0; it < 6; ++it) {
            const int c4 = it * 4 + cg;     // 0..23
            const size_t base = ((size_t)b * NC + c4 * 8) * HW + p0 + px;
            v8us pk;
            #pragma unroll
            for (int j = 0; j < 8; ++j) pk[j] = vp[base + (size_t)j * HW];
            *reinterpret_cast<v8us*>(&bt[px * 192 + ((c4 ^ (px & 7)) << 3)]) = pk;
        }
    }
    __syncthreads();

    const int w = t >> 6, l = t & 63, lr = l & 15, lg = l >> 4;
    const int oc0 = w * 48;                 // 4 waves x 48 oc = 192

    v4f acc[4][3];
    #pragma unroll
    for (int mi = 0; mi < 4; ++mi)
        #pragma unroll
        for (int ni = 0; ni < 3; ++ni)
            acc[mi][ni] = (v4f){0.f, 0.f, 0.f, 0.f};

    #pragma unroll
    for (int ks = 0; ks < 6; ++ks) {
        const int k = ks * 32 + lg * 8;
        const int c4 = ks * 4 + lg;
        v8bf a[4];
        #pragma unroll
        for (int mi = 0; mi < 4; ++mi) {
            const int px = mi * 16 + lr;
            a[mi] = *reinterpret_cast<const v8bf*>(&bt[px * 192 + ((c4 ^ (px & 7)) << 3)]);
        }
        #pragma unroll
        for (int ni = 0; ni < 3; ++ni) {
            const int oc = oc0 + ni * 16 + lr;
            const v8bf bw = *reinterpret_cast<const v8bf*>(&Mb[((size_t)b * NC + oc) * NC + k]);
            #pragma unroll
            for (int mi = 0; mi < 4; ++mi)
                acc[mi][ni] = __builtin_amdgcn_mfma_f32_16x16x32_bf16(a[mi], bw, acc[mi][ni], 0, 0, 0);
        }
    }

    // epilogue: stage [192 oc][64 px] fp32 tile; stream full 256B runs per oc-row
    __syncthreads();   // bt reads done; reuse smemf as et
    float* et = smemf;
    #pragma unroll
    for (int mi = 0; mi < 4; ++mi)
        #pragma unroll
        for (int ni = 0; ni < 3; ++ni) {
            const int oc = oc0 + ni * 16 + lr;
            const int u = mi * 4 + lg;          // 16B px-unit 0..15
            const int su = u ^ (oc & 15);
            *reinterpret_cast<v4f*>(&et[oc * 64 + su * 4]) = acc[mi][ni];
        }
    __syncthreads();
    // 192 oc x 16 units = 3072 16B-chunks; 256 thr x 12 rounds; 16 lanes cover one 256B oc-row
    #pragma unroll
    for (int rd = 0; rd < 12; ++rd) {
        const int idx = rd * 256 + t;
        const int oc = idx >> 4;
        const int u = idx & 15;
        const int su = u ^ (oc & 15);
        v4f v = *reinterpret_cast<v4f*>(&et[oc * 64 + su * 4]);
        *reinterpret_cast<v4f*>(&out[((size_t)b * NC + oc) * HW + p0 + u * 4]) = v;
    }
}

extern "C" void kernel_launch(void* const* d_in, const int* in_sizes, int n_in,
                              void* d_out, int out_size, void* d_ws, size_t ws_size,
                              hipStream_t stream)
{
    (void)in_sizes; (void)n_in; (void)out_size;
    const float* x      = (const float*)d_in[0];
    const float* f      = (const float*)d_in[1];
    const float* w_qkv  = (const float*)d_in[2];
    const float* w_dw   = (const float*)d_in[3];
    const float* w_proj = (const float*)d_in[4];
    const float* temp   = (const float*)d_in[5];

    // ws layout: fixed small stuff + v first, then adaptive qkv staging region
    char* ws = (char*)d_ws;
    u16*   vws      = (u16*)(ws);                      // 8*192*16384*2 = 50,331,648
    u16*   wb       = (u16*)(ws + 50331648);           // 576*192*2     =    221,184
    float* sumsq    = (float*)(ws + 50552832);         // 8*384*4       =     12,288
    float* partials = (float*)(ws + 50565120);         // 8*4*16*2304*4 =  4,718,592
    u16*   Mb       = (u16*)(ws + 55283712);           // 8*192*192*2   =    589,824
    const size_t FIXED = 55873536;
    const size_t PERB  = (size_t)NOC * HW * 2;         // 18,874,368 per batch
    u16*   qkv_raw  = (u16*)(ws + FIXED);

    int g = 1;
    if (ws_size > FIXED + PERB) {
        size_t avail = (ws_size - FIXED) / PERB;
        g = (int)(avail > 8 ? 8 : avail);
        if (g < 1) g = 1;
    }

    u16* qk_scratch = (u16*)d_out;   // q,k planes (bf16) — exactly fills d_out, consumed before final GEMM
    float* out      = (float*)d_out;

    hipLaunchKernelGGL(k_cvt_w, dim3(432), dim3(256), 0, stream, w_qkv, wb, NOC * NC);
    for (int b0 = 0; b0 < NB; b0 += g) {
        const int nb = (b0 + g <= NB) ? g : (NB - b0);
        hipLaunchKernelGGL(k_gemm_qkv, dim3(HW / 128, nb), dim3(1024), 0, stream, x, f, wb, qkv_raw, b0);
        hipLaunchKernelGGL(k_dw, dim3(NOC, nb), dim3(512), 0, stream, qkv_raw, w_dw, qk_scratch, vws, sumsq, b0);
    }
    hipLaunchKernelGGL(k_attn, dim3(NCHUNK, NH, NB), dim3(256), 0, stream, qk_scratch, partials);
    hipLaunchKernelGGL(k_smx, dim3(NH, NB), dim3(256), 0, stream, partials, sumsq, w_proj, temp, Mb);
    hipLaunchKernelGGL(k_gemm_out, dim3(HW / 64, NB), dim3(256), 0, stream, vws, Mb, out);
}